// Round 9
// baseline (933.850 us; speedup 1.0000x reference)
//
#include <hip/hip_runtime.h>
#include <hip/hip_bf16.h>

#define BB   8
#define HGT  128
#define WID  128
#define CC   192
#define LLEN (HGT*WID)        // 16384
#define MM   (BB*LLEN)        // 131072
#define NF   388              // 2C + FL + 1
#define HIDN 768

typedef unsigned short us16;
typedef __attribute__((ext_vector_type(8))) short bf16x8;
typedef __attribute__((ext_vector_type(4))) float f32x4;

__device__ __forceinline__ float bf2f(us16 u) {
    return __uint_as_float(((unsigned int)u) << 16);
}
__device__ __forceinline__ us16 f2bf(float f) {
    unsigned int x = __float_as_uint(f);
    x = (x + 0x7fffu + ((x >> 16) & 1u)) >> 16;
    return (us16)x;
}
// fast gelu: tanh form via exp2-backed __expf
__device__ __forceinline__ float gelu_f(float x) {
    float u = 0.7978845608f * x * (1.0f + 0.044715f * x * x);
    float e = __expf(fminf(2.0f * u, 30.0f));
    return 0.5f * x * (1.0f + (e - 1.0f) / (e + 1.0f));
}

__device__ __forceinline__ void gload_lds16(const void* g, void* l) {
    __builtin_amdgcn_global_load_lds(
        (const __attribute__((address_space(1))) void*)g,
        (__attribute__((address_space(3))) void*)l, 16, 0, 0);
}

// ---------------- Weight convert: fp32 -> bf16, transposed ----------
__global__ __launch_bounds__(256) void wcvt_kernel(const float* __restrict__ f_w,
        const float* __restrict__ h_w, const float* __restrict__ proj_w,
        const float* __restrict__ fc1_w, const float* __restrict__ fc2_w,
        const float* __restrict__ fk0, const float* __restrict__ fk1,
        const float* __restrict__ fk2,
        us16* __restrict__ fwT, us16* __restrict__ hwB, us16* __restrict__ projT,
        us16* __restrict__ w1T, us16* __restrict__ w2T,
        us16* __restrict__ kw0T, us16* __restrict__ kw1T, us16* __restrict__ kw2T) {
    int i = blockIdx.x * 256 + threadIdx.x;
    if (i < 86016) {                       // fwT: 448 x 192 (pad rows >= 388 = 0)
        int n = i / 192, k = i % 192;
        fwT[i] = (n < NF) ? f2bf(f_w[k * NF + n]) : (us16)0;
        return;
    }
    i -= 86016;
    if (i < 36864) { hwB[i] = f2bf(h_w[i]); return; }       // h_w[o][c] is already [N][K]
    i -= 36864;
    if (i < 36864) { int n = i / 192, k = i % 192; projT[i] = f2bf(proj_w[k * CC + n]); return; }
    i -= 36864;
    if (i < 147456) { int n = i / 192, k = i % 192; w1T[i] = f2bf(fc1_w[k * HIDN + n]); return; }
    i -= 147456;
    if (i < 147456) { int n = i / 768, k = i % 768; w2T[i] = f2bf(fc2_w[k * CC + n]); return; }
    i -= 147456;
    if (i < 1728)  { int kyx = i / 192, c = i % 192; kw0T[i] = f2bf(fk0[c * 9 + kyx]);  return; }
    i -= 1728;
    if (i < 4800)  { int kyx = i / 192, c = i % 192; kw1T[i] = f2bf(fk1[c * 25 + kyx]); return; }
    i -= 4800;
    if (i < 9408)  { int kyx = i / 192, c = i % 192; kw2T[i] = f2bf(fk2[c * 49 + kyx]); return; }
}

// ---------------- Fused LN1 + f-proj GEMM: one block per 128-row M-tile -------
// LN in-kernel -> swizzled LDS; A-frags hoisted to VGPR; loop 7 n-tiles.
__global__ __launch_bounds__(256) void lngemm_kernel(const float* __restrict__ x,
        const float* __restrict__ lg, const float* __restrict__ lb,
        const us16* __restrict__ fwT, const float* __restrict__ bias,
        us16* __restrict__ out_q, us16* __restrict__ out_ctx, us16* __restrict__ out_g) {
    __shared__ __align__(16) char Asm[128 * 384];
    int id = blockIdx.x;
    int mt = (id & 7) * 128 + (id >> 3);    // XCD-chunked
    int m0 = mt * 128;
    int tid = threadIdx.x, lane = tid & 63, w = tid >> 6;
    int wm = w >> 1, wn = w & 1, g4 = lane >> 4, lr = lane & 15;
    float gg0 = lg[lane], gg1 = lg[lane + 64], gg2 = lg[lane + 128];
    float bb0 = lb[lane], bb1 = lb[lane + 64], bb2 = lb[lane + 128];
    for (int rr = 0; rr < 32; rr++) {
        int rb = w * 32 + rr;
        const float* p = x + (size_t)(m0 + rb) * CC;
        float v0 = p[lane], v1 = p[lane + 64], v2 = p[lane + 128];
        float s1 = v0 + v1 + v2, s2 = v0*v0 + v1*v1 + v2*v2;
        for (int o = 32; o; o >>= 1) { s1 += __shfl_xor(s1, o); s2 += __shfl_xor(s2, o); }
        float m = s1 * (1.0f / 192.0f);
        float inv = rsqrtf(s2 * (1.0f / 192.0f) - m * m + 1e-5f);
        int sw = (rb & 7) << 4;
        *(us16*)(Asm + ((rb * 384 + lane * 2)         ^ sw)) = f2bf((v0 - m) * inv * gg0 + bb0);
        *(us16*)(Asm + ((rb * 384 + (lane + 64) * 2)  ^ sw)) = f2bf((v1 - m) * inv * gg1 + bb1);
        *(us16*)(Asm + ((rb * 384 + (lane + 128) * 2) ^ sw)) = f2bf((v2 - m) * inv * gg2 + bb2);
    }
    __syncthreads();
    bf16x8 af[6][4];
    #pragma unroll
    for (int kk = 0; kk < 6; kk++) {
        int k2 = (kk * 32 + g4 * 8) * 2;
        #pragma unroll
        for (int i = 0; i < 4; i++) {
            int row = wm * 64 + i * 16 + lr;
            af[kk][i] = *(const bf16x8*)(Asm + row * 384 + (k2 ^ ((row & 7) << 4)));
        }
    }
    int orow = m0 + wm * 64;
    #pragma unroll
    for (int nt = 0; nt < 7; nt++) {
        int n0 = nt * 64;
        const us16* Bb = fwT + (size_t)(n0 + wn * 32 + lr) * CC;
        f32x4 acc[4][2] = {};
        #pragma unroll
        for (int kk = 0; kk < 6; kk++) {
            #pragma unroll
            for (int j = 0; j < 2; j++) {
                bf16x8 bv = *(const bf16x8*)(Bb + (size_t)j * 16 * CC + kk * 32 + g4 * 8);
                #pragma unroll
                for (int i = 0; i < 4; i++)
                    acc[i][j] = __builtin_amdgcn_mfma_f32_16x16x32_bf16(af[kk][i], bv, acc[i][j], 0, 0, 0);
            }
        }
        #pragma unroll
        for (int i = 0; i < 4; i++) {
            #pragma unroll
            for (int j = 0; j < 2; j++) {
                int ncol = n0 + wn * 32 + j * 16;
                int cc   = ncol + lr;
                #pragma unroll
                for (int r = 0; r < 4; r++) {
                    int row = orow + i * 16 + g4 * 4 + r;
                    float v = acc[i][j][r];
                    if (ncol < 192)      out_q[(size_t)row * CC + cc]            = f2bf(v + bias[cc]);
                    else if (ncol < 384) out_ctx[(size_t)row * CC + (cc - 192)]  = f2bf(v + bias[cc]);
                    else if (cc < NF)    out_g[(size_t)row * 4 + (cc - 384)]     = f2bf(v + bias[cc]);
                }
            }
        }
    }
}

// ---------------- Depthwise conv v3: cg-major lanes (coalesced), fused chain --
// LVL 0 (F=3): out = gelu(conv3(in))                      [writes c3 plane]
// LVL 1 (F=5): out = gelu(conv5(c3)); ctx = g0*c3c + g1*out  [writes c5 + ctx01]
// LVL 2 (F=7): c7 = gelu(conv7(c5)); ctx += g2*c7; block partial sums of c7
template<int F, int LVL>
__global__ __launch_bounds__(256) void convv2_kernel(const us16* __restrict__ in,
                            us16* __restrict__ outp,
                            us16* __restrict__ ctx,
                            const us16* __restrict__ gates,
                            const us16* __restrict__ kwT,
                            float* __restrict__ partial) {
    constexpr int P  = F / 2;
    constexpr int NW = F + 3;          // row vectors per ky: XT + F - 1, XT = 4
    __shared__ __align__(16) us16 kws[F * F * CC];   // LVL2: reused as psum later
    int tid = threadIdx.x;
    int lb  = (blockIdx.x & 7) * 384 + (blockIdx.x >> 3);  // XCD owns one image
    for (int t = tid; t < F * F * CC / 8; t += 256)
        ((bf16x8*)kws)[t] = ((const bf16x8*)kwT)[t];
    __syncthreads();
    int idx  = lb * 256 + tid;                    // over (MM/4)*24
    int cg   = idx % 24;
    int rest = idx / 24;                          // b*4096 + y*32 + x4
    int x4 = rest & 31;
    int y0 = (rest >> 5) & 127;
    int b  = rest >> 12;
    int x0 = x4 * 4;
    float acc[4][8] = {};
    const us16* inb = in + (size_t)b * LLEN * CC + cg * 8;
    for (int ky = 0; ky < F; ky++) {
        int yy = y0 + ky - P;
        if (yy < 0 || yy > 127) continue;
        const us16* rp = inb + (size_t)yy * WID * CC;
        float rv[NW][8];
        #pragma unroll
        for (int i = 0; i < NW; i++) {
            int xx = x0 - P + i;
            if (xx >= 0 && xx <= 127) {
                bf16x8 v = *(const bf16x8*)(rp + (size_t)xx * CC);
                #pragma unroll
                for (int j = 0; j < 8; j++) rv[i][j] = bf2f((us16)v[j]);
            } else {
                #pragma unroll
                for (int j = 0; j < 8; j++) rv[i][j] = 0.0f;
            }
        }
        #pragma unroll
        for (int kx = 0; kx < F; kx++) {
            bf16x8 wv = *(const bf16x8*)(kws + (ky * F + kx) * CC + cg * 8);
            float w[8];
            #pragma unroll
            for (int j = 0; j < 8; j++) w[j] = bf2f((us16)wv[j]);
            #pragma unroll
            for (int px = 0; px < 4; px++)
                #pragma unroll
                for (int j = 0; j < 8; j++)
                    acc[px][j] += rv[kx + px][j] * w[j];
        }
    }
    int pix = (b * HGT + y0) * WID + x0;
    size_t obase = (size_t)pix * CC + cg * 8;
    if constexpr (LVL == 0) {
        #pragma unroll
        for (int px = 0; px < 4; px++) {
            bf16x8 ov;
            #pragma unroll
            for (int j = 0; j < 8; j++) ov[j] = (short)f2bf(gelu_f(acc[px][j]));
            *(bf16x8*)(outp + obase + (size_t)px * CC) = ov;
        }
    } else if constexpr (LVL == 1) {
        #pragma unroll
        for (int px = 0; px < 4; px++) {
            unsigned gv = *(const unsigned*)(gates + (size_t)(pix + px) * 4);
            float g0 = bf2f((us16)(gv & 0xffffu));
            float g1 = bf2f((us16)(gv >> 16));
            // c3 center = input plane at this output pixel
            bf16x8 c3v = *(const bf16x8*)(inb + ((size_t)y0 * WID + x0 + px) * CC);
            bf16x8 ov, cv;
            #pragma unroll
            for (int j = 0; j < 8; j++) {
                float v5 = gelu_f(acc[px][j]);
                ov[j] = (short)f2bf(v5);
                cv[j] = (short)f2bf(g0 * bf2f((us16)c3v[j]) + g1 * v5);
            }
            *(bf16x8*)(outp + obase + (size_t)px * CC) = ov;
            *(bf16x8*)(ctx  + obase + (size_t)px * CC) = cv;
        }
    } else {
        float csum[8] = {};
        #pragma unroll
        for (int px = 0; px < 4; px++) {
            float g2 = bf2f(gates[(size_t)(pix + px) * 4 + 2]);
            bf16x8 cv = *(const bf16x8*)(ctx + obase + (size_t)px * CC);
            bf16x8 ov;
            #pragma unroll
            for (int j = 0; j < 8; j++) {
                float c7 = gelu_f(acc[px][j]);
                csum[j] += c7;
                ov[j] = (short)f2bf(bf2f((us16)cv[j]) + g2 * c7);
            }
            *(bf16x8*)(ctx + obase + (size_t)px * CC) = ov;
        }
        __syncthreads();                             // done with kws taps
        float (*psum)[8] = (float (*)[8])kws;        // overlay (needs 8 KB <= 18.4 KB)
        #pragma unroll
        for (int j = 0; j < 8; j++) psum[tid][j] = csum[j];
        __syncthreads();
        if (tid < 192) {
            int j = tid & 7, cgw = tid >> 3;
            int t0 = (cgw - (lb * 256) % 24) % 24;
            if (t0 < 0) t0 += 24;
            float s = 0.0f;
            for (int t = t0; t < 256; t += 24) s += psum[t][j];
            partial[(size_t)lb * CC + tid] = s;   // c == tid (cgw*8 + j)
        }
    }
}

// ---------------- Global mean finish + hg = h_w @ gelu(mean), 1 block/image ---
__global__ __launch_bounds__(192) void gmean2_kernel(const float* __restrict__ partial,
                                                     const float* __restrict__ h_w,
                                                     float* __restrict__ hg) {
    __shared__ float ctxg[CC];
    int b = blockIdx.x, c = threadIdx.x;
    const float* pb = partial + (size_t)b * 384 * CC + c;
    float s = 0.0f;
    for (int k = 0; k < 384; k++) s += pb[(size_t)k * CC];
    ctxg[c] = gelu_f(s * (1.0f / 16384.0f));
    __syncthreads();
    float a = 0.0f;
    for (int c2 = 0; c2 < CC; c2++) a += h_w[c * CC + c2] * ctxg[c2];
    hg[b * CC + c] = a;
}

// ---------------- Fused modulator + proj GEMMs: one block per 128-row M-tile --
// GEMM1: mod = ctx_all @ h_w^T (+h_b + g3*hg), * q -> xq (into same LDS)
// GEMM2: out = xq @ projT + proj_b + x  (f32)
__global__ __launch_bounds__(256) void modproj_kernel(const us16* __restrict__ A,
        const us16* __restrict__ hwB, const float* __restrict__ h_b,
        const us16* __restrict__ projT, const float* __restrict__ proj_b,
        const us16* __restrict__ q_in, const us16* __restrict__ gates_in,
        const float* __restrict__ hg, const float* __restrict__ x_in,
        float* __restrict__ out_f) {
    __shared__ __align__(16) char Asm[128 * 384];
    int id = blockIdx.x;
    int mt = (id & 7) * 128 + (id >> 3);
    int m0 = mt * 128;
    int tid = threadIdx.x, lane = tid & 63, w = tid >> 6;
    int wm = w >> 1, wn = w & 1, g4 = lane >> 4, lr = lane & 15;

    const char* Agl = (const char*)(A + (size_t)m0 * CC);
    #pragma unroll
    for (int i = 0; i < 12; i++) {
        int wl   = w * 12 + i;
        int byte = wl * 1024 + lane * 16;
        int row  = byte / 384;
        int off  = byte - row * 384;
        int soff = off ^ ((row & 7) << 4);
        gload_lds16(Agl + (size_t)row * 384 + soff, Asm + wl * 1024);
    }
    __syncthreads();
    // ---- GEMM1: wave covers 64 rows x 96 cols ----
    {
        f32x4 acc[4][6] = {};
        #pragma unroll
        for (int kk = 0; kk < 6; kk++) {
            int k2 = (kk * 32 + g4 * 8) * 2;
            bf16x8 a[4];
            #pragma unroll
            for (int i = 0; i < 4; i++) {
                int row = wm * 64 + i * 16 + lr;
                a[i] = *(const bf16x8*)(Asm + row * 384 + (k2 ^ ((row & 7) << 4)));
            }
            #pragma unroll
            for (int j = 0; j < 6; j++) {
                bf16x8 bv = *(const bf16x8*)(hwB + (size_t)(wn * 96 + j * 16 + lr) * CC + kk * 32 + g4 * 8);
                #pragma unroll
                for (int i = 0; i < 4; i++)
                    acc[i][j] = __builtin_amdgcn_mfma_f32_16x16x32_bf16(a[i], bv, acc[i][j], 0, 0, 0);
            }
        }
        __syncthreads();      // all waves done reading A
        int bidx = m0 >> 14;
        #pragma unroll
        for (int i = 0; i < 4; i++) {
            #pragma unroll
            for (int r = 0; r < 4; r++) {
                int rl  = wm * 64 + i * 16 + g4 * 4 + r;
                int row = m0 + rl;
                float g3 = bf2f(gates_in[(size_t)row * 4 + 3]);
                int sw = (rl & 7) << 4;
                #pragma unroll
                for (int j = 0; j < 6; j++) {
                    int cc = wn * 96 + j * 16 + lr;
                    float val = (acc[i][j][r] + h_b[cc] + g3 * hg[bidx * CC + cc])
                                * bf2f(q_in[(size_t)row * CC + cc]);
                    *(us16*)(Asm + ((rl * 384 + cc * 2) ^ sw)) = f2bf(val);
                }
            }
        }
    }
    __syncthreads();
    // ---- GEMM2 ----
    {
        f32x4 acc[4][6] = {};
        #pragma unroll
        for (int kk = 0; kk < 6; kk++) {
            int k2 = (kk * 32 + g4 * 8) * 2;
            bf16x8 a[4];
            #pragma unroll
            for (int i = 0; i < 4; i++) {
                int row = wm * 64 + i * 16 + lr;
                a[i] = *(const bf16x8*)(Asm + row * 384 + (k2 ^ ((row & 7) << 4)));
            }
            #pragma unroll
            for (int j = 0; j < 6; j++) {
                bf16x8 bv = *(const bf16x8*)(projT + (size_t)(wn * 96 + j * 16 + lr) * CC + kk * 32 + g4 * 8);
                #pragma unroll
                for (int i = 0; i < 4; i++)
                    acc[i][j] = __builtin_amdgcn_mfma_f32_16x16x32_bf16(a[i], bv, acc[i][j], 0, 0, 0);
            }
        }
        #pragma unroll
        for (int i = 0; i < 4; i++) {
            #pragma unroll
            for (int j = 0; j < 6; j++) {
                int cc = wn * 96 + j * 16 + lr;
                float pb = proj_b[cc];
                #pragma unroll
                for (int r = 0; r < 4; r++) {
                    int row = m0 + wm * 64 + i * 16 + g4 * 4 + r;
                    out_f[(size_t)row * CC + cc] = acc[i][j][r] + pb + x_in[(size_t)row * CC + cc];
                }
            }
        }
    }
}

// ---------------- Fused LN2 + fc1: one block per 128-row M-tile, loop 6 nt ----
__global__ __launch_bounds__(512) void fc1ln_kernel(const float* __restrict__ x1,
        const float* __restrict__ lg, const float* __restrict__ lb,
        const us16* __restrict__ w1T, const float* __restrict__ bias,
        us16* __restrict__ hid0, us16* __restrict__ hid1) {
    __shared__ __align__(16) char Asm[128 * 384];
    int id  = blockIdx.x;
    int swz = (id & 7) * 64 + (id >> 3);   // 512 blocks, XCD-chunked
    int m0  = swz * 128;
    int tid = threadIdx.x, lane = tid & 63, w = tid >> 6;
    int wm = w >> 2, wn = w & 3, g4 = lane >> 4, lr = lane & 15;
    float gg0 = lg[lane], gg1 = lg[lane + 64], gg2 = lg[lane + 128];
    float bb0 = lb[lane], bb1 = lb[lane + 64], bb2 = lb[lane + 128];
    for (int rr = 0; rr < 16; rr++) {
        int rb = w * 16 + rr;
        const float* p = x1 + (size_t)(m0 + rb) * CC;
        float v0 = p[lane], v1 = p[lane + 64], v2 = p[lane + 128];
        float s1 = v0 + v1 + v2, s2 = v0*v0 + v1*v1 + v2*v2;
        for (int o = 32; o; o >>= 1) { s1 += __shfl_xor(s1, o); s2 += __shfl_xor(s2, o); }
        float m = s1 * (1.0f / 192.0f);
        float inv = rsqrtf(s2 * (1.0f / 192.0f) - m * m + 1e-5f);
        int sw = (rb & 7) << 4;
        *(us16*)(Asm + ((rb * 384 + lane * 2)         ^ sw)) = f2bf((v0 - m) * inv * gg0 + bb0);
        *(us16*)(Asm + ((rb * 384 + (lane + 64) * 2)  ^ sw)) = f2bf((v1 - m) * inv * gg1 + bb1);
        *(us16*)(Asm + ((rb * 384 + (lane + 128) * 2) ^ sw)) = f2bf((v2 - m) * inv * gg2 + bb2);
    }
    __syncthreads();
    us16* hidp = (m0 & 32768) ? hid1 : hid0;
    int ml = (m0 & 32767) + wm * 64;
    for (int nt = 0; nt < 6; nt++) {
        int n0 = nt * 128;
        const us16* Bb = w1T + (size_t)(n0 + wn * 32 + lr) * CC;
        f32x4 acc[4][2] = {};
        #pragma unroll
        for (int kk = 0; kk < 6; kk++) {
            int k2 = (kk * 32 + g4 * 8) * 2;
            bf16x8 a[4];
            #pragma unroll
            for (int i = 0; i < 4; i++) {
                int row = wm * 64 + i * 16 + lr;
                a[i] = *(const bf16x8*)(Asm + row * 384 + (k2 ^ ((row & 7) << 4)));
            }
            #pragma unroll
            for (int j = 0; j < 2; j++) {
                bf16x8 bv = *(const bf16x8*)(Bb + (size_t)j * 16 * CC + kk * 32 + g4 * 8);
                #pragma unroll
                for (int i = 0; i < 4; i++)
                    acc[i][j] = __builtin_amdgcn_mfma_f32_16x16x32_bf16(a[i], bv, acc[i][j], 0, 0, 0);
            }
        }
        #pragma unroll
        for (int i = 0; i < 4; i++) {
            #pragma unroll
            for (int j = 0; j < 2; j++) {
                int col = n0 + wn * 32 + j * 16 + lr;
                float fb = bias[col];
                #pragma unroll
                for (int r = 0; r < 4; r++) {
                    int row = ml + i * 16 + g4 * 4 + r;
                    hidp[(size_t)row * HIDN + col] = f2bf(gelu_f(acc[i][j][r] + fb));
                }
            }
        }
    }
}

// ---------------- fc2: out += hid @ w2 + b2, 128x192 tile, K=768 in 4 chunks --
__global__ __launch_bounds__(512, 4) void fc2_kernel(const us16* __restrict__ hid0,
        const us16* __restrict__ hid1, const us16* __restrict__ w2T,
        const float* __restrict__ bias, float* __restrict__ io) {
    __shared__ __align__(16) char Asm[128 * 384];
    int m0 = blockIdx.x * 128;
    int tid = threadIdx.x, lane = tid & 63, w = tid >> 6;
    int wm = w >> 2, wn = w & 3, g = lane >> 4, lr = lane & 15;
    const us16* hidp = (m0 & 32768) ? hid1 : hid0;
    const char* Agl = (const char*)(hidp + (size_t)(m0 & 32767) * HIDN);

    f32x4 acc[4][3] = {};
    for (int c = 0; c < 4; c++) {
        #pragma unroll
        for (int i = 0; i < 6; i++) {
            int wl   = w * 6 + i;
            int byte = wl * 1024 + lane * 16;
            int row  = byte / 384;
            int off  = byte - row * 384;
            int soff = off ^ ((row & 7) << 4);
            gload_lds16(Agl + (size_t)row * 1536 + c * 384 + soff, Asm + wl * 1024);
        }
        __syncthreads();                       // DMA drained (vmcnt 0)
        #pragma unroll
        for (int kk = 0; kk < 6; kk++) {
            int k2 = (kk * 32 + g * 8) * 2;
            bf16x8 a[4];
            #pragma unroll
            for (int i = 0; i < 4; i++) {
                int row = wm * 64 + i * 16 + lr;
                a[i] = *(const bf16x8*)(Asm + row * 384 + (k2 ^ ((row & 7) << 4)));
            }
            #pragma unroll
            for (int j = 0; j < 3; j++) {
                bf16x8 bv = *(const bf16x8*)(w2T + (size_t)(wn * 48 + j * 16 + lr) * HIDN
                                             + c * 192 + kk * 32 + g * 8);
                acc[0][j] = __builtin_amdgcn_mfma_f32_16x16x32_bf16(a[0], bv, acc[0][j], 0, 0, 0);
                acc[1][j] = __builtin_amdgcn_mfma_f32_16x16x32_bf16(a[1], bv, acc[1][j], 0, 0, 0);
                acc[2][j] = __builtin_amdgcn_mfma_f32_16x16x32_bf16(a[2], bv, acc[2][j], 0, 0, 0);
                acc[3][j] = __builtin_amdgcn_mfma_f32_16x16x32_bf16(a[3], bv, acc[3][j], 0, 0, 0);
            }
        }
        __syncthreads();                       // safe to overwrite Asm
    }
    #pragma unroll
    for (int i = 0; i < 4; i++) {
        #pragma unroll
        for (int j = 0; j < 3; j++) {
            int col = wn * 48 + j * 16 + lr;
            float fb = bias[col];
            #pragma unroll
            for (int r = 0; r < 4; r++) {
                int row = m0 + wm * 64 + i * 16 + g * 4 + r;
                io[(size_t)row * CC + col] += acc[i][j][r] + fb;
            }
        }
    }
}

extern "C" void kernel_launch(void* const* d_in, const int* in_sizes, int n_in,
                              void* d_out, int out_size, void* d_ws, size_t ws_size,
                              hipStream_t stream) {
    const float* x      = (const float*)d_in[0];
    const float* ln1_g  = (const float*)d_in[1];
    const float* ln1_b  = (const float*)d_in[2];
    const float* f_w    = (const float*)d_in[3];
    const float* f_b    = (const float*)d_in[4];
    const float* fk0    = (const float*)d_in[5];
    const float* fk1    = (const float*)d_in[6];
    const float* fk2    = (const float*)d_in[7];
    const float* h_w    = (const float*)d_in[8];
    const float* h_b    = (const float*)d_in[9];
    const float* proj_w = (const float*)d_in[10];
    const float* proj_b = (const float*)d_in[11];
    const float* ln2_g  = (const float*)d_in[12];
    const float* ln2_b  = (const float*)d_in[13];
    const float* fc1_w  = (const float*)d_in[14];
    const float* fc1_b  = (const float*)d_in[15];
    const float* fc2_w  = (const float*)d_in[16];
    const float* fc2_b  = (const float*)d_in[17];
    float* outp = (float*)d_out;

    char* ws = (char*)d_ws;
    const size_t S = (size_t)MM * CC * 2;          // 50,331,648 B (one bf16 plane)
    us16* t_buf   = (us16*)(ws);                   // hid plane 0 (MLP)
    us16* q_buf   = (us16*)(ws + S);               // q
    us16* ctx_all = (us16*)(ws + 2 * S);           // ctx01/ctx_all ; later hid plane 1
    us16* gates   = (us16*)(ws + 3 * S);
    float* hg      = (float*)(ws + 3 * S + 1048576);
    us16* fwT   = (us16*)(ws + 3 * S + 1048576 + 786432 + 6144);
    us16* hwB   = fwT + 86016;
    us16* projT = hwB + 36864;
    us16* w1T   = projT + 36864;
    us16* w2T   = w1T + 147456;
    us16* kw0T  = w2T + 147456;
    us16* kw1T  = kw0T + 1728;
    us16* kw2T  = kw1T + 4800;
    // conv planes live in d_out (dead until modproj rewrites it fully)
    us16* ctxA = (us16*)d_out;                          // conv input, then c5
    us16* ctxB = (us16*)d_out + (size_t)MM * CC;        // c3
    float* partial = (float*)ctxB;                      // reused after c3 is dead

    wcvt_kernel<<<1839, 256, 0, stream>>>(f_w, h_w, proj_w, fc1_w, fc2_w,
                                          fk0, fk1, fk2,
                                          fwT, hwB, projT, w1T, w2T, kw0T, kw1T, kw2T);

    lngemm_kernel<<<1024, 256, 0, stream>>>(x, ln1_g, ln1_b, fwT, f_b,
                                            q_buf, ctxA, gates);

    convv2_kernel<3, 0><<<3072, 256, 0, stream>>>(ctxA, ctxB, nullptr, nullptr, kw0T, nullptr);
    convv2_kernel<5, 1><<<3072, 256, 0, stream>>>(ctxB, ctxA, ctx_all, gates, kw1T, nullptr);
    convv2_kernel<7, 2><<<3072, 256, 0, stream>>>(ctxA, nullptr, ctx_all, gates, kw2T, partial);

    gmean2_kernel<<<8, 192, 0, stream>>>(partial, h_w, hg);

    modproj_kernel<<<1024, 256, 0, stream>>>(ctx_all, hwB, h_b, projT, proj_b,
                                             q_buf, gates, hg, x, outp);

    // ---- MLP: fused LN2+fc1, then fc2, per M-half ----
    for (int h = 0; h < 2; h++) {
        const float* x1h = outp + (size_t)h * 65536 * CC;
        fc1ln_kernel<<<512, 512, 0, stream>>>(x1h, ln2_g, ln2_b, w1T, fc1_b,
                                              t_buf, ctx_all);
        fc2_kernel<<<512, 512, 0, stream>>>(t_buf, ctx_all, w2T, fc2_b,
                                            (float*)x1h);
    }
}

// Round 10
// 704.436 us; speedup vs baseline: 1.3257x; 1.3257x over previous
//
#include <hip/hip_runtime.h>
#include <hip/hip_bf16.h>

#define BB   8
#define HGT  128
#define WID  128
#define CC   192
#define LLEN (HGT*WID)        // 16384
#define MM   (BB*LLEN)        // 131072
#define NF   388              // 2C + FL + 1
#define HIDN 768

typedef unsigned short us16;
typedef __attribute__((ext_vector_type(8))) short bf16x8;
typedef __attribute__((ext_vector_type(4))) float f32x4;
typedef __attribute__((ext_vector_type(2))) float f32x2;

__device__ __forceinline__ float bf2f(us16 u) {
    return __uint_as_float(((unsigned int)u) << 16);
}
__device__ __forceinline__ us16 f2bf(float f) {
    unsigned int x = __float_as_uint(f);
    x = (x + 0x7fffu + ((x >> 16) & 1u)) >> 16;
    return (us16)x;
}
// fast gelu: tanh form via exp2-backed __expf
__device__ __forceinline__ float gelu_f(float x) {
    float u = 0.7978845608f * x * (1.0f + 0.044715f * x * x);
    float e = __expf(fminf(2.0f * u, 30.0f));
    return 0.5f * x * (1.0f + (e - 1.0f) / (e + 1.0f));
}
// unpack one dword (2 bf16) -> f32x2 (elem0 = low half, elem1 = high half)
__device__ __forceinline__ f32x2 unpk2(unsigned d) {
    f32x2 r;
    r[0] = __uint_as_float(d << 16);
    r[1] = __uint_as_float(d & 0xffff0000u);
    return r;
}

__device__ __forceinline__ void gload_lds16(const void* g, void* l) {
    __builtin_amdgcn_global_load_lds(
        (const __attribute__((address_space(1))) void*)g,
        (__attribute__((address_space(3))) void*)l, 16, 0, 0);
}

// ---------------- Weight convert: fp32 -> bf16, transposed ----------
__global__ __launch_bounds__(256) void wcvt_kernel(const float* __restrict__ f_w,
        const float* __restrict__ h_w, const float* __restrict__ proj_w,
        const float* __restrict__ fc1_w, const float* __restrict__ fc2_w,
        const float* __restrict__ fk0, const float* __restrict__ fk1,
        const float* __restrict__ fk2,
        us16* __restrict__ fwT, us16* __restrict__ hwB, us16* __restrict__ projT,
        us16* __restrict__ w1T, us16* __restrict__ w2T,
        us16* __restrict__ kw0T, us16* __restrict__ kw1T, us16* __restrict__ kw2T) {
    int i = blockIdx.x * 256 + threadIdx.x;
    if (i < 86016) {                       // fwT: 448 x 192 (pad rows >= 388 = 0)
        int n = i / 192, k = i % 192;
        fwT[i] = (n < NF) ? f2bf(f_w[k * NF + n]) : (us16)0;
        return;
    }
    i -= 86016;
    if (i < 36864) { hwB[i] = f2bf(h_w[i]); return; }       // h_w[o][c] is already [N][K]
    i -= 36864;
    if (i < 36864) { int n = i / 192, k = i % 192; projT[i] = f2bf(proj_w[k * CC + n]); return; }
    i -= 36864;
    if (i < 147456) { int n = i / 192, k = i % 192; w1T[i] = f2bf(fc1_w[k * HIDN + n]); return; }
    i -= 147456;
    if (i < 147456) { int n = i / 768, k = i % 768; w2T[i] = f2bf(fc2_w[k * CC + n]); return; }
    i -= 147456;
    if (i < 1728)  { int kyx = i / 192, c = i % 192; kw0T[i] = f2bf(fk0[c * 9 + kyx]);  return; }
    i -= 1728;
    if (i < 4800)  { int kyx = i / 192, c = i % 192; kw1T[i] = f2bf(fk1[c * 25 + kyx]); return; }
    i -= 4800;
    if (i < 9408)  { int kyx = i / 192, c = i % 192; kw2T[i] = f2bf(fk2[c * 49 + kyx]); return; }
}

// ---------------- LayerNorm: fp32 in -> bf16 out (wave per row) ----------------
__global__ __launch_bounds__(256) void ln_kernel(const float* __restrict__ in,
                                                 const float* __restrict__ g,
                                                 const float* __restrict__ b,
                                                 us16* __restrict__ out) {
    int wid  = threadIdx.x >> 6;
    int lane = threadIdx.x & 63;
    int row  = blockIdx.x * 4 + wid;
    const float* p = in + (size_t)row * CC;
    float v0 = p[lane], v1 = p[lane + 64], v2 = p[lane + 128];
    float s1 = v0 + v1 + v2;
    float s2 = v0*v0 + v1*v1 + v2*v2;
    for (int o = 32; o; o >>= 1) { s1 += __shfl_xor(s1, o); s2 += __shfl_xor(s2, o); }
    float m   = s1 * (1.0f / 192.0f);
    float var = s2 * (1.0f / 192.0f) - m * m;
    float inv = rsqrtf(var + 1e-5f);
    us16* q = out + (size_t)row * CC;
    q[lane]       = f2bf((v0 - m) * inv * g[lane]       + b[lane]);
    q[lane + 64]  = f2bf((v1 - m) * inv * g[lane + 64]  + b[lane + 64]);
    q[lane + 128] = f2bf((v2 - m) * inv * g[lane + 128] + b[lane + 128]);
}

// ---------------- MFMA GEMM: LDS-staged A, K=192, 128x64 tile, 4 waves --------
template<int MODE>
__global__ __launch_bounds__(256) void mgemm_kernel(const us16* __restrict__ A,
        const us16* __restrict__ Bt, const float* __restrict__ bias,
        us16* __restrict__ out_q, us16* __restrict__ out_ctx, us16* __restrict__ out_g,
        const us16* __restrict__ q_in, const us16* __restrict__ gates_in,
        const float* __restrict__ hg, const float* __restrict__ x_in,
        float* __restrict__ out_f) {
    __shared__ __align__(16) char Asm[128 * 384];
    constexpr int NT = (MODE == 0) ? 7 : 3;
    int id  = blockIdx.x;
    int xcd = id & 7;
    int s   = id >> 3;
    int mt  = xcd * 128 + s / NT;          // all N-tiles of an M-tile on one XCD
    int nt  = s % NT;
    int m0 = mt * 128, n0 = nt * 64;
    int tid = threadIdx.x, lane = tid & 63, w = tid >> 6;
    int wm = w >> 1, wn = w & 1, g = lane >> 4, lr = lane & 15;

    const char* Agl = (const char*)(A + (size_t)m0 * CC);
    #pragma unroll
    for (int i = 0; i < 12; i++) {
        int wl   = w * 12 + i;                 // 0..47
        int byte = wl * 1024 + lane * 16;
        int row  = byte / 384;
        int off  = byte - row * 384;
        int soff = off ^ ((row & 7) << 4);
        gload_lds16(Agl + (size_t)row * 384 + soff, Asm + wl * 1024);
    }
    const us16* Bb = Bt + (size_t)(n0 + wn * 32 + lr) * CC;
    bf16x8 bfr[6][2];
    #pragma unroll
    for (int kk = 0; kk < 6; kk++)
        #pragma unroll
        for (int j = 0; j < 2; j++)
            bfr[kk][j] = *(const bf16x8*)(Bb + (size_t)j * 16 * CC + kk * 32 + g * 8);

    __syncthreads();

    f32x4 acc[4][2] = {};
    #pragma unroll
    for (int kk = 0; kk < 6; kk++) {
        int k2 = (kk * 32 + g * 8) * 2;
        bf16x8 a[4];
        #pragma unroll
        for (int i = 0; i < 4; i++) {
            int row = wm * 64 + i * 16 + lr;
            a[i] = *(const bf16x8*)(Asm + row * 384 + (k2 ^ ((row & 7) << 4)));
        }
        #pragma unroll
        for (int j = 0; j < 2; j++) {
            acc[0][j] = __builtin_amdgcn_mfma_f32_16x16x32_bf16(a[0], bfr[kk][j], acc[0][j], 0, 0, 0);
            acc[1][j] = __builtin_amdgcn_mfma_f32_16x16x32_bf16(a[1], bfr[kk][j], acc[1][j], 0, 0, 0);
            acc[2][j] = __builtin_amdgcn_mfma_f32_16x16x32_bf16(a[2], bfr[kk][j], acc[2][j], 0, 0, 0);
            acc[3][j] = __builtin_amdgcn_mfma_f32_16x16x32_bf16(a[3], bfr[kk][j], acc[3][j], 0, 0, 0);
        }
    }
    int orow = m0 + wm * 64;
    #pragma unroll
    for (int i = 0; i < 4; i++) {
        #pragma unroll
        for (int j = 0; j < 2; j++) {
            int ncol = n0 + wn * 32 + j * 16;
            int cc   = ncol + lr;
            #pragma unroll
            for (int r = 0; r < 4; r++) {
                int row = orow + i * 16 + g * 4 + r;
                float v = acc[i][j][r];
                if (MODE == 0) {
                    if (ncol < 192)      out_q[(size_t)row * CC + cc]          = f2bf(v + bias[cc]);
                    else if (ncol < 384) out_ctx[(size_t)row * CC + (cc - 192)] = f2bf(v + bias[cc]);
                    else if (cc < NF)    out_g[(size_t)row * 4 + (cc - 384)]    = f2bf(v + bias[cc]);
                } else if (MODE == 1) {
                    int bidx = row >> 14;
                    float val = v + bias[cc] + bf2f(gates_in[(size_t)row * 4 + 3]) * hg[bidx * CC + cc];
                    val *= bf2f(q_in[(size_t)row * CC + cc]);
                    out_q[(size_t)row * CC + cc] = f2bf(val);
                } else {
                    out_f[(size_t)row * CC + cc] = v + bias[cc] + x_in[(size_t)row * CC + cc];
                }
            }
        }
    }
}

// ---------------- Depthwise conv v4: cg-major lanes, packed-f32 (v_pk_fma) ----
// LVL 0 (F=3): out = gelu(conv3(in))                      [writes c3 plane]
// LVL 1 (F=5): out = gelu(conv5(c3)); ctx = g0*c3c + g1*out  [writes c5 + ctx01]
// LVL 2 (F=7): c7 = gelu(conv7(c5)); ctx += g2*c7; block partial sums of c7
template<int F, int LVL>
__global__ __launch_bounds__(256) void convv2_kernel(const us16* __restrict__ in,
                            us16* __restrict__ outp,
                            us16* __restrict__ ctx,
                            const us16* __restrict__ gates,
                            const us16* __restrict__ kwT,
                            float* __restrict__ partial) {
    constexpr int P  = F / 2;
    constexpr int NW = F + 3;          // row vectors per ky: XT + F - 1, XT = 4
    __shared__ __align__(16) us16 kws[F * F * CC];   // LVL2: reused as psum later
    int tid = threadIdx.x;
    int lb  = (blockIdx.x & 7) * 384 + (blockIdx.x >> 3);  // XCD owns one image
    for (int t = tid; t < F * F * CC / 8; t += 256)
        ((bf16x8*)kws)[t] = ((const bf16x8*)kwT)[t];
    __syncthreads();
    int idx  = lb * 256 + tid;                    // over (MM/4)*24
    int cg   = idx % 24;
    int rest = idx / 24;                          // b*4096 + y*32 + x4
    int x4 = rest & 31;
    int y0 = (rest >> 5) & 127;
    int b  = rest >> 12;
    int x0 = x4 * 4;
    f32x2 acc[4][4] = {};
    const us16* inb = in + (size_t)b * LLEN * CC + cg * 8;
    for (int ky = 0; ky < F; ky++) {
        int yy = y0 + ky - P;
        if (yy < 0 || yy > 127) continue;
        const us16* rp = inb + (size_t)yy * WID * CC;
        f32x2 rv[NW][4];
        #pragma unroll
        for (int i = 0; i < NW; i++) {
            int xx = x0 - P + i;
            if (xx >= 0 && xx <= 127) {
                uint4 v = *(const uint4*)(rp + (size_t)xx * CC);
                rv[i][0] = unpk2(v.x); rv[i][1] = unpk2(v.y);
                rv[i][2] = unpk2(v.z); rv[i][3] = unpk2(v.w);
            } else {
                rv[i][0] = rv[i][1] = rv[i][2] = rv[i][3] = (f32x2){0.0f, 0.0f};
            }
        }
        #pragma unroll
        for (int kx = 0; kx < F; kx++) {
            uint4 wv = *(const uint4*)(kws + (ky * F + kx) * CC + cg * 8);
            f32x2 w0 = unpk2(wv.x), w1 = unpk2(wv.y), w2 = unpk2(wv.z), w3 = unpk2(wv.w);
            #pragma unroll
            for (int px = 0; px < 4; px++) {
                acc[px][0] += rv[kx + px][0] * w0;
                acc[px][1] += rv[kx + px][1] * w1;
                acc[px][2] += rv[kx + px][2] * w2;
                acc[px][3] += rv[kx + px][3] * w3;
            }
        }
    }
    int pix = (b * HGT + y0) * WID + x0;
    size_t obase = (size_t)pix * CC + cg * 8;
    if constexpr (LVL == 0) {
        #pragma unroll
        for (int px = 0; px < 4; px++) {
            uint4 ov;
            unsigned* po = &ov.x;
            #pragma unroll
            for (int q = 0; q < 4; q++)
                po[q] = (unsigned)f2bf(gelu_f(acc[px][q][0]))
                      | ((unsigned)f2bf(gelu_f(acc[px][q][1])) << 16);
            *(uint4*)(outp + obase + (size_t)px * CC) = ov;
        }
    } else if constexpr (LVL == 1) {
        #pragma unroll
        for (int px = 0; px < 4; px++) {
            unsigned gv = *(const unsigned*)(gates + (size_t)(pix + px) * 4);
            float g0 = bf2f((us16)(gv & 0xffffu));
            float g1 = bf2f((us16)(gv >> 16));
            // c3 center = input plane at this output pixel
            uint4 c3v = *(const uint4*)(inb + ((size_t)y0 * WID + x0 + px) * CC);
            const unsigned* pc = &c3v.x;
            uint4 ov, cv;
            unsigned* po = &ov.x;
            unsigned* pv = &cv.x;
            #pragma unroll
            for (int q = 0; q < 4; q++) {
                f32x2 c3 = unpk2(pc[q]);
                float v5a = gelu_f(acc[px][q][0]);
                float v5b = gelu_f(acc[px][q][1]);
                po[q] = (unsigned)f2bf(v5a) | ((unsigned)f2bf(v5b) << 16);
                pv[q] = (unsigned)f2bf(g0 * c3[0] + g1 * v5a)
                      | ((unsigned)f2bf(g0 * c3[1] + g1 * v5b) << 16);
            }
            *(uint4*)(outp + obase + (size_t)px * CC) = ov;
            *(uint4*)(ctx  + obase + (size_t)px * CC) = cv;
        }
    } else {
        f32x2 csum[4] = {};
        #pragma unroll
        for (int px = 0; px < 4; px++) {
            float g2 = bf2f(gates[(size_t)(pix + px) * 4 + 2]);
            uint4 cv = *(const uint4*)(ctx + obase + (size_t)px * CC);
            const unsigned* pc = &cv.x;
            uint4 ov;
            unsigned* po = &ov.x;
            #pragma unroll
            for (int q = 0; q < 4; q++) {
                f32x2 cprev = unpk2(pc[q]);
                float c7a = gelu_f(acc[px][q][0]);
                float c7b = gelu_f(acc[px][q][1]);
                csum[q][0] += c7a;
                csum[q][1] += c7b;
                po[q] = (unsigned)f2bf(cprev[0] + g2 * c7a)
                      | ((unsigned)f2bf(cprev[1] + g2 * c7b) << 16);
            }
            *(uint4*)(ctx + obase + (size_t)px * CC) = ov;
        }
        __syncthreads();                             // done with kws taps
        float (*psum)[8] = (float (*)[8])kws;        // overlay (8 KB <= 18.4 KB)
        #pragma unroll
        for (int q = 0; q < 4; q++) {
            psum[tid][q * 2]     = csum[q][0];
            psum[tid][q * 2 + 1] = csum[q][1];
        }
        __syncthreads();
        if (tid < 192) {
            int j = tid & 7, cgw = tid >> 3;
            int t0 = (cgw - (lb * 256) % 24) % 24;
            if (t0 < 0) t0 += 24;
            float s = 0.0f;
            for (int t = t0; t < 256; t += 24) s += psum[t][j];
            partial[(size_t)lb * CC + tid] = s;   // c == tid (cgw*8 + j)
        }
    }
}

// ---------------- Global mean finish + hg = h_w @ gelu(mean), 1 block/image ---
__global__ __launch_bounds__(192) void gmean2_kernel(const float* __restrict__ partial,
                                                     const float* __restrict__ h_w,
                                                     float* __restrict__ hg) {
    __shared__ float ctxg[CC];
    int b = blockIdx.x, c = threadIdx.x;
    const float* pb = partial + (size_t)b * 384 * CC + c;
    float s = 0.0f;
    for (int k = 0; k < 384; k++) s += pb[(size_t)k * CC];
    ctxg[c] = gelu_f(s * (1.0f / 16384.0f));
    __syncthreads();
    float a = 0.0f;
    for (int c2 = 0; c2 < CC; c2++) a += h_w[c * CC + c2] * ctxg[c2];
    hg[b * CC + c] = a;
}

// ---------------- fc1: hid = gelu(ln2 @ w1 + b1), 128x128 tile, 8 waves -------
__global__ __launch_bounds__(512, 4) void fc1_kernel(const us16* __restrict__ A,
        const us16* __restrict__ w1T, const float* __restrict__ bias,
        us16* __restrict__ hid0, us16* __restrict__ hid1) {
    __shared__ __align__(16) char Asm[128 * 384];
    int id  = blockIdx.x;
    int swz = (id & 7) * 384 + (id >> 3);   // XCD-chunked: m-contiguous per XCD
    int mt  = swz / 6, nt = swz % 6;
    int m0 = mt * 128;
    int n0 = nt * 128;
    int tid = threadIdx.x, lane = tid & 63, w = tid >> 6;
    int wm = w >> 2, wn = w & 3, g = lane >> 4, lr = lane & 15;

    const char* Agl = (const char*)(A + (size_t)m0 * CC);
    #pragma unroll
    for (int i = 0; i < 6; i++) {
        int wl   = w * 6 + i;                  // 0..47
        int byte = wl * 1024 + lane * 16;
        int row  = byte / 384;
        int off  = byte - row * 384;
        int soff = off ^ ((row & 7) << 4);
        gload_lds16(Agl + (size_t)row * 384 + soff, Asm + wl * 1024);
    }
    const us16* Bb = w1T + (size_t)(n0 + wn * 32 + lr) * CC;
    bf16x8 bfr[6][2];
    #pragma unroll
    for (int kk = 0; kk < 6; kk++)
        #pragma unroll
        for (int j = 0; j < 2; j++)
            bfr[kk][j] = *(const bf16x8*)(Bb + (size_t)j * 16 * CC + kk * 32 + g * 8);

    __syncthreads();

    f32x4 acc[4][2] = {};
    #pragma unroll
    for (int kk = 0; kk < 6; kk++) {
        int k2 = (kk * 32 + g * 8) * 2;
        bf16x8 a[4];
        #pragma unroll
        for (int i = 0; i < 4; i++) {
            int row = wm * 64 + i * 16 + lr;
            a[i] = *(const bf16x8*)(Asm + row * 384 + (k2 ^ ((row & 7) << 4)));
        }
        #pragma unroll
        for (int j = 0; j < 2; j++) {
            acc[0][j] = __builtin_amdgcn_mfma_f32_16x16x32_bf16(a[0], bfr[kk][j], acc[0][j], 0, 0, 0);
            acc[1][j] = __builtin_amdgcn_mfma_f32_16x16x32_bf16(a[1], bfr[kk][j], acc[1][j], 0, 0, 0);
            acc[2][j] = __builtin_amdgcn_mfma_f32_16x16x32_bf16(a[2], bfr[kk][j], acc[2][j], 0, 0, 0);
            acc[3][j] = __builtin_amdgcn_mfma_f32_16x16x32_bf16(a[3], bfr[kk][j], acc[3][j], 0, 0, 0);
        }
    }
    us16* hidp = (m0 & 32768) ? hid1 : hid0;
    int ml = (m0 & 32767) + wm * 64;
    #pragma unroll
    for (int i = 0; i < 4; i++) {
        #pragma unroll
        for (int j = 0; j < 2; j++) {
            int col = n0 + wn * 32 + j * 16 + lr;
            float fb = bias[col];
            #pragma unroll
            for (int r = 0; r < 4; r++) {
                int row = ml + i * 16 + g * 4 + r;
                hidp[(size_t)row * HIDN + col] = f2bf(gelu_f(acc[i][j][r] + fb));
            }
        }
    }
}

// ---------------- fc2: out += hid @ w2 + b2, 128x192 tile, K=768 in 4 chunks --
__global__ __launch_bounds__(512, 4) void fc2_kernel(const us16* __restrict__ hid0,
        const us16* __restrict__ hid1, const us16* __restrict__ w2T,
        const float* __restrict__ bias, float* __restrict__ io) {
    __shared__ __align__(16) char Asm[128 * 384];
    int m0 = blockIdx.x * 128;
    int tid = threadIdx.x, lane = tid & 63, w = tid >> 6;
    int wm = w >> 2, wn = w & 3, g = lane >> 4, lr = lane & 15;
    const us16* hidp = (m0 & 32768) ? hid1 : hid0;
    const char* Agl = (const char*)(hidp + (size_t)(m0 & 32767) * HIDN);

    f32x4 acc[4][3] = {};
    for (int c = 0; c < 4; c++) {
        #pragma unroll
        for (int i = 0; i < 6; i++) {
            int wl   = w * 6 + i;
            int byte = wl * 1024 + lane * 16;
            int row  = byte / 384;
            int off  = byte - row * 384;
            int soff = off ^ ((row & 7) << 4);
            gload_lds16(Agl + (size_t)row * 1536 + c * 384 + soff, Asm + wl * 1024);
        }
        __syncthreads();                       // DMA drained (vmcnt 0)
        #pragma unroll
        for (int kk = 0; kk < 6; kk++) {
            int k2 = (kk * 32 + g * 8) * 2;
            bf16x8 a[4];
            #pragma unroll
            for (int i = 0; i < 4; i++) {
                int row = wm * 64 + i * 16 + lr;
                a[i] = *(const bf16x8*)(Asm + row * 384 + (k2 ^ ((row & 7) << 4)));
            }
            #pragma unroll
            for (int j = 0; j < 3; j++) {
                bf16x8 bv = *(const bf16x8*)(w2T + (size_t)(wn * 48 + j * 16 + lr) * HIDN
                                             + c * 192 + kk * 32 + g * 8);
                acc[0][j] = __builtin_amdgcn_mfma_f32_16x16x32_bf16(a[0], bv, acc[0][j], 0, 0, 0);
                acc[1][j] = __builtin_amdgcn_mfma_f32_16x16x32_bf16(a[1], bv, acc[1][j], 0, 0, 0);
                acc[2][j] = __builtin_amdgcn_mfma_f32_16x16x32_bf16(a[2], bv, acc[2][j], 0, 0, 0);
                acc[3][j] = __builtin_amdgcn_mfma_f32_16x16x32_bf16(a[3], bv, acc[3][j], 0, 0, 0);
            }
        }
        __syncthreads();                       // safe to overwrite Asm
    }
    #pragma unroll
    for (int i = 0; i < 4; i++) {
        #pragma unroll
        for (int j = 0; j < 3; j++) {
            int col = wn * 48 + j * 16 + lr;
            float fb = bias[col];
            #pragma unroll
            for (int r = 0; r < 4; r++) {
                int row = m0 + wm * 64 + i * 16 + g * 4 + r;
                io[(size_t)row * CC + col] += acc[i][j][r] + fb;
            }
        }
    }
}

extern "C" void kernel_launch(void* const* d_in, const int* in_sizes, int n_in,
                              void* d_out, int out_size, void* d_ws, size_t ws_size,
                              hipStream_t stream) {
    const float* x      = (const float*)d_in[0];
    const float* ln1_g  = (const float*)d_in[1];
    const float* ln1_b  = (const float*)d_in[2];
    const float* f_w    = (const float*)d_in[3];
    const float* f_b    = (const float*)d_in[4];
    const float* fk0    = (const float*)d_in[5];
    const float* fk1    = (const float*)d_in[6];
    const float* fk2    = (const float*)d_in[7];
    const float* h_w    = (const float*)d_in[8];
    const float* h_b    = (const float*)d_in[9];
    const float* proj_w = (const float*)d_in[10];
    const float* proj_b = (const float*)d_in[11];
    const float* ln2_g  = (const float*)d_in[12];
    const float* ln2_b  = (const float*)d_in[13];
    const float* fc1_w  = (const float*)d_in[14];
    const float* fc1_b  = (const float*)d_in[15];
    const float* fc2_w  = (const float*)d_in[16];
    const float* fc2_b  = (const float*)d_in[17];
    float* outp = (float*)d_out;

    char* ws = (char*)d_ws;
    const size_t S = (size_t)MM * CC * 2;          // 50,331,648 B (one bf16 plane)
    us16* t_buf   = (us16*)(ws);                   // t / xq ; later hid plane 0
    us16* q_buf   = (us16*)(ws + S);               // q ; later ln2 output
    us16* ctx_all = (us16*)(ws + 2 * S);           // ctx01/ctx_all ; later hid plane 1
    us16* gates   = (us16*)(ws + 3 * S);
    float* hg      = (float*)(ws + 3 * S + 1048576);
    us16* fwT   = (us16*)(ws + 3 * S + 1048576 + 786432 + 6144);
    us16* hwB   = fwT + 86016;
    us16* projT = hwB + 36864;
    us16* w1T   = projT + 36864;
    us16* w2T   = w1T + 147456;
    us16* kw0T  = w2T + 147456;
    us16* kw1T  = kw0T + 1728;
    us16* kw2T  = kw1T + 4800;
    // conv planes live in d_out (dead until mgemm<2> rewrites it fully)
    us16* ctxA = (us16*)d_out;                          // conv input, then c5
    us16* ctxB = (us16*)d_out + (size_t)MM * CC;        // c3
    float* partial = (float*)ctxB;                      // reused after c3 is dead

    wcvt_kernel<<<1839, 256, 0, stream>>>(f_w, h_w, proj_w, fc1_w, fc2_w,
                                          fk0, fk1, fk2,
                                          fwT, hwB, projT, w1T, w2T, kw0T, kw1T, kw2T);

    ln_kernel<<<MM / 4, 256, 0, stream>>>(x, ln1_g, ln1_b, t_buf);

    mgemm_kernel<0><<<8 * 128 * 7, 256, 0, stream>>>(
        t_buf, fwT, f_b, q_buf, ctxA, gates, nullptr, nullptr, nullptr, nullptr, nullptr);

    convv2_kernel<3, 0><<<3072, 256, 0, stream>>>(ctxA, ctxB, nullptr, nullptr, kw0T, nullptr);
    convv2_kernel<5, 1><<<3072, 256, 0, stream>>>(ctxB, ctxA, ctx_all, gates, kw1T, nullptr);
    convv2_kernel<7, 2><<<3072, 256, 0, stream>>>(ctxA, nullptr, ctx_all, gates, kw2T, partial);

    gmean2_kernel<<<8, 192, 0, stream>>>(partial, h_w, hg);

    mgemm_kernel<1><<<8 * 128 * 3, 256, 0, stream>>>(
        ctx_all, hwB, h_b, t_buf, nullptr, nullptr, q_buf, gates, hg, nullptr, nullptr);

    mgemm_kernel<2><<<8 * 128 * 3, 256, 0, stream>>>(
        t_buf, projT, proj_b, nullptr, nullptr, nullptr, nullptr, nullptr, nullptr, x, outp);

    // ---- MLP as two staged GEMMs over two M-halves ----
    ln_kernel<<<MM / 4, 256, 0, stream>>>(outp, ln2_g, ln2_b, q_buf);

    for (int h = 0; h < 2; h++) {
        const us16* Ah = q_buf + (size_t)h * 65536 * CC;
        float* ioh     = outp  + (size_t)h * 65536 * CC;
        fc1_kernel<<<3072, 512, 0, stream>>>(Ah, w1T, fc1_b, t_buf, ctx_all);
        fc2_kernel<<<512, 512, 0, stream>>>(t_buf, ctx_all, w2T, fc2_b, ioh);
    }
}

// Round 11
// 687.852 us; speedup vs baseline: 1.3576x; 1.0241x over previous
//
#include <hip/hip_runtime.h>
#include <hip/hip_bf16.h>

#define BB   8
#define HGT  128
#define WID  128
#define CC   192
#define LLEN (HGT*WID)        // 16384
#define MM   (BB*LLEN)        // 131072
#define NF   388              // 2C + FL + 1
#define HIDN 768

typedef unsigned short us16;
typedef __attribute__((ext_vector_type(8))) short bf16x8;
typedef __attribute__((ext_vector_type(4))) float f32x4;
typedef __attribute__((ext_vector_type(2))) float f32x2;

__device__ __forceinline__ float bf2f(us16 u) {
    return __uint_as_float(((unsigned int)u) << 16);
}
__device__ __forceinline__ us16 f2bf(float f) {
    unsigned int x = __float_as_uint(f);
    x = (x + 0x7fffu + ((x >> 16) & 1u)) >> 16;
    return (us16)x;
}
// fast gelu: tanh form via exp2-backed __expf
__device__ __forceinline__ float gelu_f(float x) {
    float u = 0.7978845608f * x * (1.0f + 0.044715f * x * x);
    float e = __expf(fminf(2.0f * u, 30.0f));
    return 0.5f * x * (1.0f + (e - 1.0f) / (e + 1.0f));
}
// unpack one dword (2 bf16) -> f32x2 (elem0 = low half, elem1 = high half)
__device__ __forceinline__ f32x2 unpk2(unsigned d) {
    f32x2 r;
    r[0] = __uint_as_float(d << 16);
    r[1] = __uint_as_float(d & 0xffff0000u);
    return r;
}

__device__ __forceinline__ void gload_lds16(const void* g, void* l) {
    __builtin_amdgcn_global_load_lds(
        (const __attribute__((address_space(1))) void*)g,
        (__attribute__((address_space(3))) void*)l, 16, 0, 0);
}

// ---------------- Weight convert: fp32 -> bf16, transposed ----------
__global__ __launch_bounds__(256) void wcvt_kernel(const float* __restrict__ f_w,
        const float* __restrict__ h_w, const float* __restrict__ proj_w,
        const float* __restrict__ fc1_w, const float* __restrict__ fc2_w,
        const float* __restrict__ fk0, const float* __restrict__ fk1,
        const float* __restrict__ fk2,
        us16* __restrict__ fwT, us16* __restrict__ hwB, us16* __restrict__ projT,
        us16* __restrict__ w1T, us16* __restrict__ w2T,
        us16* __restrict__ kw0T, us16* __restrict__ kw1T, us16* __restrict__ kw2T) {
    int i = blockIdx.x * 256 + threadIdx.x;
    if (i < 86016) {                       // fwT: 448 x 192 (pad rows >= 388 = 0)
        int n = i / 192, k = i % 192;
        fwT[i] = (n < NF) ? f2bf(f_w[k * NF + n]) : (us16)0;
        return;
    }
    i -= 86016;
    if (i < 36864) { hwB[i] = f2bf(h_w[i]); return; }       // h_w[o][c] is already [N][K]
    i -= 36864;
    if (i < 36864) { int n = i / 192, k = i % 192; projT[i] = f2bf(proj_w[k * CC + n]); return; }
    i -= 36864;
    if (i < 147456) { int n = i / 192, k = i % 192; w1T[i] = f2bf(fc1_w[k * HIDN + n]); return; }
    i -= 147456;
    if (i < 147456) { int n = i / 768, k = i % 768; w2T[i] = f2bf(fc2_w[k * CC + n]); return; }
    i -= 147456;
    if (i < 1728)  { int kyx = i / 192, c = i % 192; kw0T[i] = f2bf(fk0[c * 9 + kyx]);  return; }
    i -= 1728;
    if (i < 4800)  { int kyx = i / 192, c = i % 192; kw1T[i] = f2bf(fk1[c * 25 + kyx]); return; }
    i -= 4800;
    if (i < 9408)  { int kyx = i / 192, c = i % 192; kw2T[i] = f2bf(fk2[c * 49 + kyx]); return; }
}

// ---------------- LayerNorm: fp32 in -> bf16 out (wave per row) ----------------
__global__ __launch_bounds__(256) void ln_kernel(const float* __restrict__ in,
                                                 const float* __restrict__ g,
                                                 const float* __restrict__ b,
                                                 us16* __restrict__ out) {
    int wid  = threadIdx.x >> 6;
    int lane = threadIdx.x & 63;
    int row  = blockIdx.x * 4 + wid;
    const float* p = in + (size_t)row * CC;
    float v0 = p[lane], v1 = p[lane + 64], v2 = p[lane + 128];
    float s1 = v0 + v1 + v2;
    float s2 = v0*v0 + v1*v1 + v2*v2;
    for (int o = 32; o; o >>= 1) { s1 += __shfl_xor(s1, o); s2 += __shfl_xor(s2, o); }
    float m   = s1 * (1.0f / 192.0f);
    float var = s2 * (1.0f / 192.0f) - m * m;
    float inv = rsqrtf(var + 1e-5f);
    us16* q = out + (size_t)row * CC;
    q[lane]       = f2bf((v0 - m) * inv * g[lane]       + b[lane]);
    q[lane + 64]  = f2bf((v1 - m) * inv * g[lane + 64]  + b[lane + 64]);
    q[lane + 128] = f2bf((v2 - m) * inv * g[lane + 128] + b[lane + 128]);
}

// ---------------- MFMA GEMM v3: stage A once, loop n-tiles (barrier-free) ----
template<int MODE>
__global__ __launch_bounds__(256) void mgemm_kernel(const us16* __restrict__ A,
        const us16* __restrict__ Bt, const float* __restrict__ bias,
        us16* __restrict__ out_q, us16* __restrict__ out_ctx, us16* __restrict__ out_g,
        const us16* __restrict__ q_in, const us16* __restrict__ gates_in,
        const float* __restrict__ hg, const float* __restrict__ x_in,
        float* __restrict__ out_f) {
    __shared__ __align__(16) char Asm[128 * 384];
    constexpr int NT = (MODE == 0) ? 7 : 3;
    int id  = blockIdx.x;                  // 1024 blocks, one per M-tile
    int mt  = (id & 7) * 128 + (id >> 3);  // XCD-chunked
    int m0  = mt * 128;
    int tid = threadIdx.x, lane = tid & 63, w = tid >> 6;
    int wm = w >> 1, wn = w & 1, g = lane >> 4, lr = lane & 15;

    const char* Agl = (const char*)(A + (size_t)m0 * CC);
    #pragma unroll
    for (int i = 0; i < 12; i++) {
        int wl   = w * 12 + i;                 // 0..47
        int byte = wl * 1024 + lane * 16;
        int row  = byte / 384;
        int off  = byte - row * 384;
        int soff = off ^ ((row & 7) << 4);
        gload_lds16(Agl + (size_t)row * 384 + soff, Asm + wl * 1024);
    }
    __syncthreads();                       // LDS read-only after this point

    int orow = m0 + wm * 64;
    int bidx = m0 >> 14;
    for (int nt = 0; nt < NT; nt++) {
        int n0 = nt * 64;
        const us16* Bb = Bt + (size_t)(n0 + wn * 32 + lr) * CC;
        bf16x8 bfr[6][2];
        #pragma unroll
        for (int kk = 0; kk < 6; kk++)
            #pragma unroll
            for (int j = 0; j < 2; j++)
                bfr[kk][j] = *(const bf16x8*)(Bb + (size_t)j * 16 * CC + kk * 32 + g * 8);

        f32x4 acc[4][2] = {};
        #pragma unroll
        for (int kk = 0; kk < 6; kk++) {
            int k2 = (kk * 32 + g * 8) * 2;
            bf16x8 a[4];
            #pragma unroll
            for (int i = 0; i < 4; i++) {
                int row = wm * 64 + i * 16 + lr;
                a[i] = *(const bf16x8*)(Asm + row * 384 + (k2 ^ ((row & 7) << 4)));
            }
            #pragma unroll
            for (int j = 0; j < 2; j++) {
                acc[0][j] = __builtin_amdgcn_mfma_f32_16x16x32_bf16(a[0], bfr[kk][j], acc[0][j], 0, 0, 0);
                acc[1][j] = __builtin_amdgcn_mfma_f32_16x16x32_bf16(a[1], bfr[kk][j], acc[1][j], 0, 0, 0);
                acc[2][j] = __builtin_amdgcn_mfma_f32_16x16x32_bf16(a[2], bfr[kk][j], acc[2][j], 0, 0, 0);
                acc[3][j] = __builtin_amdgcn_mfma_f32_16x16x32_bf16(a[3], bfr[kk][j], acc[3][j], 0, 0, 0);
            }
        }
        #pragma unroll
        for (int i = 0; i < 4; i++) {
            #pragma unroll
            for (int j = 0; j < 2; j++) {
                int ncol = n0 + wn * 32 + j * 16;
                int cc   = ncol + lr;
                #pragma unroll
                for (int r = 0; r < 4; r++) {
                    int row = orow + i * 16 + g * 4 + r;
                    float v = acc[i][j][r];
                    if (MODE == 0) {
                        if (ncol < 192)      out_q[(size_t)row * CC + cc]          = f2bf(v + bias[cc]);
                        else if (ncol < 384) out_ctx[(size_t)row * CC + (cc - 192)] = f2bf(v + bias[cc]);
                        else if (cc < NF)    out_g[(size_t)row * 4 + (cc - 384)]    = f2bf(v + bias[cc]);
                    } else if (MODE == 1) {
                        float val = v + bias[cc] + bf2f(gates_in[(size_t)row * 4 + 3]) * hg[bidx * CC + cc];
                        val *= bf2f(q_in[(size_t)row * CC + cc]);
                        out_q[(size_t)row * CC + cc] = f2bf(val);
                    } else {
                        out_f[(size_t)row * CC + cc] = v + bias[cc] + x_in[(size_t)row * CC + cc];
                    }
                }
            }
        }
    }
}

// ---------------- Depthwise conv v4: cg-major lanes, packed-f32 (v_pk_fma) ----
// LVL 0 (F=3): out = gelu(conv3(in))                      [writes c3 plane]
// LVL 1 (F=5): out = gelu(conv5(c3)); ctx = g0*c3c + g1*out  [writes c5 + ctx01]
// LVL 2 (F=7): c7 = gelu(conv7(c5)); ctx += g2*c7; block partial sums of c7
template<int F, int LVL>
__global__ __launch_bounds__(256) void convv2_kernel(const us16* __restrict__ in,
                            us16* __restrict__ outp,
                            us16* __restrict__ ctx,
                            const us16* __restrict__ gates,
                            const us16* __restrict__ kwT,
                            float* __restrict__ partial) {
    constexpr int P  = F / 2;
    constexpr int NW = F + 3;          // row vectors per ky: XT + F - 1, XT = 4
    __shared__ __align__(16) us16 kws[F * F * CC];   // LVL2: reused as psum later
    int tid = threadIdx.x;
    int lb  = (blockIdx.x & 7) * 384 + (blockIdx.x >> 3);  // XCD owns one image
    for (int t = tid; t < F * F * CC / 8; t += 256)
        ((bf16x8*)kws)[t] = ((const bf16x8*)kwT)[t];
    __syncthreads();
    int idx  = lb * 256 + tid;                    // over (MM/4)*24
    int cg   = idx % 24;
    int rest = idx / 24;                          // b*4096 + y*32 + x4
    int x4 = rest & 31;
    int y0 = (rest >> 5) & 127;
    int b  = rest >> 12;
    int x0 = x4 * 4;
    f32x2 acc[4][4] = {};
    const us16* inb = in + (size_t)b * LLEN * CC + cg * 8;
    for (int ky = 0; ky < F; ky++) {
        int yy = y0 + ky - P;
        if (yy < 0 || yy > 127) continue;
        const us16* rp = inb + (size_t)yy * WID * CC;
        f32x2 rv[NW][4];
        #pragma unroll
        for (int i = 0; i < NW; i++) {
            int xx = x0 - P + i;
            if (xx >= 0 && xx <= 127) {
                uint4 v = *(const uint4*)(rp + (size_t)xx * CC);
                rv[i][0] = unpk2(v.x); rv[i][1] = unpk2(v.y);
                rv[i][2] = unpk2(v.z); rv[i][3] = unpk2(v.w);
            } else {
                rv[i][0] = rv[i][1] = rv[i][2] = rv[i][3] = (f32x2){0.0f, 0.0f};
            }
        }
        #pragma unroll
        for (int kx = 0; kx < F; kx++) {
            uint4 wv = *(const uint4*)(kws + (ky * F + kx) * CC + cg * 8);
            f32x2 w0 = unpk2(wv.x), w1 = unpk2(wv.y), w2 = unpk2(wv.z), w3 = unpk2(wv.w);
            #pragma unroll
            for (int px = 0; px < 4; px++) {
                acc[px][0] += rv[kx + px][0] * w0;
                acc[px][1] += rv[kx + px][1] * w1;
                acc[px][2] += rv[kx + px][2] * w2;
                acc[px][3] += rv[kx + px][3] * w3;
            }
        }
    }
    int pix = (b * HGT + y0) * WID + x0;
    size_t obase = (size_t)pix * CC + cg * 8;
    if constexpr (LVL == 0) {
        #pragma unroll
        for (int px = 0; px < 4; px++) {
            uint4 ov;
            unsigned* po = &ov.x;
            #pragma unroll
            for (int q = 0; q < 4; q++)
                po[q] = (unsigned)f2bf(gelu_f(acc[px][q][0]))
                      | ((unsigned)f2bf(gelu_f(acc[px][q][1])) << 16);
            *(uint4*)(outp + obase + (size_t)px * CC) = ov;
        }
    } else if constexpr (LVL == 1) {
        #pragma unroll
        for (int px = 0; px < 4; px++) {
            unsigned gv = *(const unsigned*)(gates + (size_t)(pix + px) * 4);
            float g0 = bf2f((us16)(gv & 0xffffu));
            float g1 = bf2f((us16)(gv >> 16));
            // c3 center = input plane at this output pixel
            uint4 c3v = *(const uint4*)(inb + ((size_t)y0 * WID + x0 + px) * CC);
            const unsigned* pc = &c3v.x;
            uint4 ov, cv;
            unsigned* po = &ov.x;
            unsigned* pv = &cv.x;
            #pragma unroll
            for (int q = 0; q < 4; q++) {
                f32x2 c3 = unpk2(pc[q]);
                float v5a = gelu_f(acc[px][q][0]);
                float v5b = gelu_f(acc[px][q][1]);
                po[q] = (unsigned)f2bf(v5a) | ((unsigned)f2bf(v5b) << 16);
                pv[q] = (unsigned)f2bf(g0 * c3[0] + g1 * v5a)
                      | ((unsigned)f2bf(g0 * c3[1] + g1 * v5b) << 16);
            }
            *(uint4*)(outp + obase + (size_t)px * CC) = ov;
            *(uint4*)(ctx  + obase + (size_t)px * CC) = cv;
        }
    } else {
        f32x2 csum[4] = {};
        #pragma unroll
        for (int px = 0; px < 4; px++) {
            float g2 = bf2f(gates[(size_t)(pix + px) * 4 + 2]);
            uint4 cv = *(const uint4*)(ctx + obase + (size_t)px * CC);
            const unsigned* pc = &cv.x;
            uint4 ov;
            unsigned* po = &ov.x;
            #pragma unroll
            for (int q = 0; q < 4; q++) {
                f32x2 cprev = unpk2(pc[q]);
                float c7a = gelu_f(acc[px][q][0]);
                float c7b = gelu_f(acc[px][q][1]);
                csum[q][0] += c7a;
                csum[q][1] += c7b;
                po[q] = (unsigned)f2bf(cprev[0] + g2 * c7a)
                      | ((unsigned)f2bf(cprev[1] + g2 * c7b) << 16);
            }
            *(uint4*)(ctx + obase + (size_t)px * CC) = ov;
        }
        __syncthreads();                             // done with kws taps
        float (*psum)[8] = (float (*)[8])kws;        // overlay (8 KB <= 18.4 KB)
        #pragma unroll
        for (int q = 0; q < 4; q++) {
            psum[tid][q * 2]     = csum[q][0];
            psum[tid][q * 2 + 1] = csum[q][1];
        }
        __syncthreads();
        if (tid < 192) {
            int j = tid & 7, cgw = tid >> 3;
            int t0 = (cgw - (lb * 256) % 24) % 24;
            if (t0 < 0) t0 += 24;
            float s = 0.0f;
            for (int t = t0; t < 256; t += 24) s += psum[t][j];
            partial[(size_t)lb * CC + tid] = s;   // c == tid (cgw*8 + j)
        }
    }
}

// ---------------- Global mean finish + hg = h_w @ gelu(mean), 1 block/image ---
__global__ __launch_bounds__(192) void gmean2_kernel(const float* __restrict__ partial,
                                                     const float* __restrict__ h_w,
                                                     float* __restrict__ hg) {
    __shared__ float ctxg[CC];
    int b = blockIdx.x, c = threadIdx.x;
    const float* pb = partial + (size_t)b * 384 * CC + c;
    float s = 0.0f;
    for (int k = 0; k < 384; k++) s += pb[(size_t)k * CC];
    ctxg[c] = gelu_f(s * (1.0f / 16384.0f));
    __syncthreads();
    float a = 0.0f;
    for (int c2 = 0; c2 < CC; c2++) a += h_w[c * CC + c2] * ctxg[c2];
    hg[b * CC + c] = a;
}

// ---------------- fc1: hid = gelu(ln2 @ w1 + b1), 128x128 tile, 8 waves -------
__global__ __launch_bounds__(512, 4) void fc1_kernel(const us16* __restrict__ A,
        const us16* __restrict__ w1T, const float* __restrict__ bias,
        us16* __restrict__ hid0, us16* __restrict__ hid1) {
    __shared__ __align__(16) char Asm[128 * 384];
    int id  = blockIdx.x;
    int swz = (id & 7) * 384 + (id >> 3);   // XCD-chunked: m-contiguous per XCD
    int mt  = swz / 6, nt = swz % 6;
    int m0 = mt * 128;
    int n0 = nt * 128;
    int tid = threadIdx.x, lane = tid & 63, w = tid >> 6;
    int wm = w >> 2, wn = w & 3, g = lane >> 4, lr = lane & 15;

    const char* Agl = (const char*)(A + (size_t)m0 * CC);
    #pragma unroll
    for (int i = 0; i < 6; i++) {
        int wl   = w * 6 + i;                  // 0..47
        int byte = wl * 1024 + lane * 16;
        int row  = byte / 384;
        int off  = byte - row * 384;
        int soff = off ^ ((row & 7) << 4);
        gload_lds16(Agl + (size_t)row * 384 + soff, Asm + wl * 1024);
    }
    const us16* Bb = w1T + (size_t)(n0 + wn * 32 + lr) * CC;
    bf16x8 bfr[6][2];
    #pragma unroll
    for (int kk = 0; kk < 6; kk++)
        #pragma unroll
        for (int j = 0; j < 2; j++)
            bfr[kk][j] = *(const bf16x8*)(Bb + (size_t)j * 16 * CC + kk * 32 + g * 8);

    __syncthreads();

    f32x4 acc[4][2] = {};
    #pragma unroll
    for (int kk = 0; kk < 6; kk++) {
        int k2 = (kk * 32 + g * 8) * 2;
        bf16x8 a[4];
        #pragma unroll
        for (int i = 0; i < 4; i++) {
            int row = wm * 64 + i * 16 + lr;
            a[i] = *(const bf16x8*)(Asm + row * 384 + (k2 ^ ((row & 7) << 4)));
        }
        #pragma unroll
        for (int j = 0; j < 2; j++) {
            acc[0][j] = __builtin_amdgcn_mfma_f32_16x16x32_bf16(a[0], bfr[kk][j], acc[0][j], 0, 0, 0);
            acc[1][j] = __builtin_amdgcn_mfma_f32_16x16x32_bf16(a[1], bfr[kk][j], acc[1][j], 0, 0, 0);
            acc[2][j] = __builtin_amdgcn_mfma_f32_16x16x32_bf16(a[2], bfr[kk][j], acc[2][j], 0, 0, 0);
            acc[3][j] = __builtin_amdgcn_mfma_f32_16x16x32_bf16(a[3], bfr[kk][j], acc[3][j], 0, 0, 0);
        }
    }
    us16* hidp = (m0 & 32768) ? hid1 : hid0;
    int ml = (m0 & 32767) + wm * 64;
    #pragma unroll
    for (int i = 0; i < 4; i++) {
        #pragma unroll
        for (int j = 0; j < 2; j++) {
            int col = n0 + wn * 32 + j * 16 + lr;
            float fb = bias[col];
            #pragma unroll
            for (int r = 0; r < 4; r++) {
                int row = ml + i * 16 + g * 4 + r;
                hidp[(size_t)row * HIDN + col] = f2bf(gelu_f(acc[i][j][r] + fb));
            }
        }
    }
}

// ---------------- fc2: out += hid @ w2 + b2, 128x192 tile, K=768 in 4 chunks --
__global__ __launch_bounds__(512, 4) void fc2_kernel(const us16* __restrict__ hid0,
        const us16* __restrict__ hid1, const us16* __restrict__ w2T,
        const float* __restrict__ bias, float* __restrict__ io) {
    __shared__ __align__(16) char Asm[128 * 384];
    int m0 = blockIdx.x * 128;
    int tid = threadIdx.x, lane = tid & 63, w = tid >> 6;
    int wm = w >> 2, wn = w & 3, g = lane >> 4, lr = lane & 15;
    const us16* hidp = (m0 & 32768) ? hid1 : hid0;
    const char* Agl = (const char*)(hidp + (size_t)(m0 & 32767) * HIDN);

    f32x4 acc[4][3] = {};
    for (int c = 0; c < 4; c++) {
        #pragma unroll
        for (int i = 0; i < 6; i++) {
            int wl   = w * 6 + i;
            int byte = wl * 1024 + lane * 16;
            int row  = byte / 384;
            int off  = byte - row * 384;
            int soff = off ^ ((row & 7) << 4);
            gload_lds16(Agl + (size_t)row * 1536 + c * 384 + soff, Asm + wl * 1024);
        }
        __syncthreads();                       // DMA drained (vmcnt 0)
        #pragma unroll
        for (int kk = 0; kk < 6; kk++) {
            int k2 = (kk * 32 + g * 8) * 2;
            bf16x8 a[4];
            #pragma unroll
            for (int i = 0; i < 4; i++) {
                int row = wm * 64 + i * 16 + lr;
                a[i] = *(const bf16x8*)(Asm + row * 384 + (k2 ^ ((row & 7) << 4)));
            }
            #pragma unroll
            for (int j = 0; j < 3; j++) {
                bf16x8 bv = *(const bf16x8*)(w2T + (size_t)(wn * 48 + j * 16 + lr) * HIDN
                                             + c * 192 + kk * 32 + g * 8);
                acc[0][j] = __builtin_amdgcn_mfma_f32_16x16x32_bf16(a[0], bv, acc[0][j], 0, 0, 0);
                acc[1][j] = __builtin_amdgcn_mfma_f32_16x16x32_bf16(a[1], bv, acc[1][j], 0, 0, 0);
                acc[2][j] = __builtin_amdgcn_mfma_f32_16x16x32_bf16(a[2], bv, acc[2][j], 0, 0, 0);
                acc[3][j] = __builtin_amdgcn_mfma_f32_16x16x32_bf16(a[3], bv, acc[3][j], 0, 0, 0);
            }
        }
        __syncthreads();                       // safe to overwrite Asm
    }
    #pragma unroll
    for (int i = 0; i < 4; i++) {
        #pragma unroll
        for (int j = 0; j < 3; j++) {
            int col = wn * 48 + j * 16 + lr;
            float fb = bias[col];
            #pragma unroll
            for (int r = 0; r < 4; r++) {
                int row = m0 + wm * 64 + i * 16 + g * 4 + r;
                io[(size_t)row * CC + col] += acc[i][j][r] + fb;
            }
        }
    }
}

extern "C" void kernel_launch(void* const* d_in, const int* in_sizes, int n_in,
                              void* d_out, int out_size, void* d_ws, size_t ws_size,
                              hipStream_t stream) {
    const float* x      = (const float*)d_in[0];
    const float* ln1_g  = (const float*)d_in[1];
    const float* ln1_b  = (const float*)d_in[2];
    const float* f_w    = (const float*)d_in[3];
    const float* f_b    = (const float*)d_in[4];
    const float* fk0    = (const float*)d_in[5];
    const float* fk1    = (const float*)d_in[6];
    const float* fk2    = (const float*)d_in[7];
    const float* h_w    = (const float*)d_in[8];
    const float* h_b    = (const float*)d_in[9];
    const float* proj_w = (const float*)d_in[10];
    const float* proj_b = (const float*)d_in[11];
    const float* ln2_g  = (const float*)d_in[12];
    const float* ln2_b  = (const float*)d_in[13];
    const float* fc1_w  = (const float*)d_in[14];
    const float* fc1_b  = (const float*)d_in[15];
    const float* fc2_w  = (const float*)d_in[16];
    const float* fc2_b  = (const float*)d_in[17];
    float* outp = (float*)d_out;

    char* ws = (char*)d_ws;
    const size_t S = (size_t)MM * CC * 2;          // 50,331,648 B (one bf16 plane)
    us16* t_buf   = (us16*)(ws);                   // t / xq ; later hid plane 0
    us16* q_buf   = (us16*)(ws + S);               // q ; later ln2 output
    us16* ctx_all = (us16*)(ws + 2 * S);           // ctx01/ctx_all ; later hid plane 1
    us16* gates   = (us16*)(ws + 3 * S);
    float* hg      = (float*)(ws + 3 * S + 1048576);
    us16* fwT   = (us16*)(ws + 3 * S + 1048576 + 786432 + 6144);
    us16* hwB   = fwT + 86016;
    us16* projT = hwB + 36864;
    us16* w1T   = projT + 36864;
    us16* w2T   = w1T + 147456;
    us16* kw0T  = w2T + 147456;
    us16* kw1T  = kw0T + 1728;
    us16* kw2T  = kw1T + 4800;
    // conv planes live in d_out (dead until mgemm<2> rewrites it fully)
    us16* ctxA = (us16*)d_out;                          // conv input, then c5
    us16* ctxB = (us16*)d_out + (size_t)MM * CC;        // c3
    float* partial = (float*)ctxB;                      // reused after c3 is dead

    wcvt_kernel<<<1839, 256, 0, stream>>>(f_w, h_w, proj_w, fc1_w, fc2_w,
                                          fk0, fk1, fk2,
                                          fwT, hwB, projT, w1T, w2T, kw0T, kw1T, kw2T);

    ln_kernel<<<MM / 4, 256, 0, stream>>>(x, ln1_g, ln1_b, t_buf);

    mgemm_kernel<0><<<1024, 256, 0, stream>>>(
        t_buf, fwT, f_b, q_buf, ctxA, gates, nullptr, nullptr, nullptr, nullptr, nullptr);

    convv2_kernel<3, 0><<<3072, 256, 0, stream>>>(ctxA, ctxB, nullptr, nullptr, kw0T, nullptr);
    convv2_kernel<5, 1><<<3072, 256, 0, stream>>>(ctxB, ctxA, ctx_all, gates, kw1T, nullptr);
    convv2_kernel<7, 2><<<3072, 256, 0, stream>>>(ctxA, nullptr, ctx_all, gates, kw2T, partial);

    gmean2_kernel<<<8, 192, 0, stream>>>(partial, h_w, hg);

    mgemm_kernel<1><<<1024, 256, 0, stream>>>(
        ctx_all, hwB, h_b, t_buf, nullptr, nullptr, q_buf, gates, hg, nullptr, nullptr);

    mgemm_kernel<2><<<1024, 256, 0, stream>>>(
        t_buf, projT, proj_b, nullptr, nullptr, nullptr, nullptr, nullptr, nullptr, x, outp);

    // ---- MLP as two staged GEMMs over two M-halves ----
    ln_kernel<<<MM / 4, 256, 0, stream>>>(outp, ln2_g, ln2_b, q_buf);

    for (int h = 0; h < 2; h++) {
        const us16* Ah = q_buf + (size_t)h * 65536 * CC;
        float* ioh     = outp  + (size_t)h * 65536 * CC;
        fc1_kernel<<<3072, 512, 0, stream>>>(Ah, w1T, fc1_b, t_buf, ctx_all);
        fc2_kernel<<<512, 512, 0, stream>>>(t_buf, ctx_all, w2T, fc2_b, ioh);
    }
}

// Round 12
// 635.960 us; speedup vs baseline: 1.4684x; 1.0816x over previous
//
#include <hip/hip_runtime.h>
#include <hip/hip_bf16.h>

#define BB   8
#define HGT  128
#define WID  128
#define CC   192
#define LLEN (HGT*WID)        // 16384
#define MM   (BB*LLEN)        // 131072
#define NF   388              // 2C + FL + 1
#define HIDN 768

typedef unsigned short us16;
typedef __attribute__((ext_vector_type(8))) short bf16x8;
typedef __attribute__((ext_vector_type(4))) float f32x4;
typedef __attribute__((ext_vector_type(2))) float f32x2;

__device__ __forceinline__ float bf2f(us16 u) {
    return __uint_as_float(((unsigned int)u) << 16);
}
__device__ __forceinline__ us16 f2bf(float f) {
    unsigned int x = __float_as_uint(f);
    x = (x + 0x7fffu + ((x >> 16) & 1u)) >> 16;
    return (us16)x;
}
// division-free gelu: x * sigmoid(1.59577*x*(1+0.044715x^2)) via fast rcp.
// exp overflow saturates cleanly (rcp(inf)=0), no clamp needed.
__device__ __forceinline__ float gelu_f(float x) {
    float t = x * (1.5957691f + 0.07135481f * x * x);
    float e = __expf(-t);
    return x * __builtin_amdgcn_rcpf(1.0f + e);
}
// unpack one dword (2 bf16) -> f32x2 (elem0 = low half, elem1 = high half)
__device__ __forceinline__ f32x2 unpk2(unsigned d) {
    f32x2 r;
    r[0] = __uint_as_float(d << 16);
    r[1] = __uint_as_float(d & 0xffff0000u);
    return r;
}

__device__ __forceinline__ void gload_lds16(const void* g, void* l) {
    __builtin_amdgcn_global_load_lds(
        (const __attribute__((address_space(1))) void*)g,
        (__attribute__((address_space(3))) void*)l, 16, 0, 0);
}

// ---------------- Weight convert: fp32 -> bf16, transposed ----------
__global__ __launch_bounds__(256) void wcvt_kernel(const float* __restrict__ f_w,
        const float* __restrict__ h_w, const float* __restrict__ proj_w,
        const float* __restrict__ fc1_w, const float* __restrict__ fc2_w,
        const float* __restrict__ fk0, const float* __restrict__ fk1,
        const float* __restrict__ fk2,
        us16* __restrict__ fwT, us16* __restrict__ hwB, us16* __restrict__ projT,
        us16* __restrict__ w1T, us16* __restrict__ w2T,
        us16* __restrict__ kw0T, us16* __restrict__ kw1T, us16* __restrict__ kw2T) {
    int i = blockIdx.x * 256 + threadIdx.x;
    if (i < 86016) {                       // fwT: 448 x 192 (pad rows >= 388 = 0)
        int n = i / 192, k = i % 192;
        fwT[i] = (n < NF) ? f2bf(f_w[k * NF + n]) : (us16)0;
        return;
    }
    i -= 86016;
    if (i < 36864) { hwB[i] = f2bf(h_w[i]); return; }       // h_w[o][c] is already [N][K]
    i -= 36864;
    if (i < 36864) { int n = i / 192, k = i % 192; projT[i] = f2bf(proj_w[k * CC + n]); return; }
    i -= 36864;
    if (i < 147456) { int n = i / 192, k = i % 192; w1T[i] = f2bf(fc1_w[k * HIDN + n]); return; }
    i -= 147456;
    if (i < 147456) { int n = i / 768, k = i % 768; w2T[i] = f2bf(fc2_w[k * CC + n]); return; }
    i -= 147456;
    if (i < 1728)  { int kyx = i / 192, c = i % 192; kw0T[i] = f2bf(fk0[c * 9 + kyx]);  return; }
    i -= 1728;
    if (i < 4800)  { int kyx = i / 192, c = i % 192; kw1T[i] = f2bf(fk1[c * 25 + kyx]); return; }
    i -= 4800;
    if (i < 9408)  { int kyx = i / 192, c = i % 192; kw2T[i] = f2bf(fk2[c * 49 + kyx]); return; }
}

// ---------------- LayerNorm: fp32 in -> bf16 out (wave per row) ----------------
__global__ __launch_bounds__(256) void ln_kernel(const float* __restrict__ in,
                                                 const float* __restrict__ g,
                                                 const float* __restrict__ b,
                                                 us16* __restrict__ out) {
    int wid  = threadIdx.x >> 6;
    int lane = threadIdx.x & 63;
    int row  = blockIdx.x * 4 + wid;
    const float* p = in + (size_t)row * CC;
    float v0 = p[lane], v1 = p[lane + 64], v2 = p[lane + 128];
    float s1 = v0 + v1 + v2;
    float s2 = v0*v0 + v1*v1 + v2*v2;
    for (int o = 32; o; o >>= 1) { s1 += __shfl_xor(s1, o); s2 += __shfl_xor(s2, o); }
    float m   = s1 * (1.0f / 192.0f);
    float var = s2 * (1.0f / 192.0f) - m * m;
    float inv = rsqrtf(var + 1e-5f);
    us16* q = out + (size_t)row * CC;
    q[lane]       = f2bf((v0 - m) * inv * g[lane]       + b[lane]);
    q[lane + 64]  = f2bf((v1 - m) * inv * g[lane + 64]  + b[lane + 64]);
    q[lane + 128] = f2bf((v2 - m) * inv * g[lane + 128] + b[lane + 128]);
}

// ---------------- MFMA GEMM v3: stage A once, loop n-tiles (barrier-free) ----
template<int MODE>
__global__ __launch_bounds__(256) void mgemm_kernel(const us16* __restrict__ A,
        const us16* __restrict__ Bt, const float* __restrict__ bias,
        us16* __restrict__ out_q, us16* __restrict__ out_ctx, us16* __restrict__ out_g,
        const us16* __restrict__ q_in, const us16* __restrict__ gates_in,
        const float* __restrict__ hg, const float* __restrict__ x_in,
        float* __restrict__ out_f) {
    __shared__ __align__(16) char Asm[128 * 384];
    constexpr int NT = (MODE == 0) ? 7 : 3;
    int id  = blockIdx.x;                  // 1024 blocks, one per M-tile
    int mt  = (id & 7) * 128 + (id >> 3);  // XCD-chunked
    int m0  = mt * 128;
    int tid = threadIdx.x, lane = tid & 63, w = tid >> 6;
    int wm = w >> 1, wn = w & 1, g = lane >> 4, lr = lane & 15;

    const char* Agl = (const char*)(A + (size_t)m0 * CC);
    #pragma unroll
    for (int i = 0; i < 12; i++) {
        int wl   = w * 12 + i;                 // 0..47
        int byte = wl * 1024 + lane * 16;
        int row  = byte / 384;
        int off  = byte - row * 384;
        int soff = off ^ ((row & 7) << 4);
        gload_lds16(Agl + (size_t)row * 384 + soff, Asm + wl * 1024);
    }
    __syncthreads();                       // LDS read-only after this point

    int orow = m0 + wm * 64;
    int bidx = m0 >> 14;
    for (int nt = 0; nt < NT; nt++) {
        int n0 = nt * 64;
        const us16* Bb = Bt + (size_t)(n0 + wn * 32 + lr) * CC;
        bf16x8 bfr[6][2];
        #pragma unroll
        for (int kk = 0; kk < 6; kk++)
            #pragma unroll
            for (int j = 0; j < 2; j++)
                bfr[kk][j] = *(const bf16x8*)(Bb + (size_t)j * 16 * CC + kk * 32 + g * 8);

        f32x4 acc[4][2] = {};
        #pragma unroll
        for (int kk = 0; kk < 6; kk++) {
            int k2 = (kk * 32 + g * 8) * 2;
            bf16x8 a[4];
            #pragma unroll
            for (int i = 0; i < 4; i++) {
                int row = wm * 64 + i * 16 + lr;
                a[i] = *(const bf16x8*)(Asm + row * 384 + (k2 ^ ((row & 7) << 4)));
            }
            #pragma unroll
            for (int j = 0; j < 2; j++) {
                acc[0][j] = __builtin_amdgcn_mfma_f32_16x16x32_bf16(a[0], bfr[kk][j], acc[0][j], 0, 0, 0);
                acc[1][j] = __builtin_amdgcn_mfma_f32_16x16x32_bf16(a[1], bfr[kk][j], acc[1][j], 0, 0, 0);
                acc[2][j] = __builtin_amdgcn_mfma_f32_16x16x32_bf16(a[2], bfr[kk][j], acc[2][j], 0, 0, 0);
                acc[3][j] = __builtin_amdgcn_mfma_f32_16x16x32_bf16(a[3], bfr[kk][j], acc[3][j], 0, 0, 0);
            }
        }
        #pragma unroll
        for (int i = 0; i < 4; i++) {
            #pragma unroll
            for (int j = 0; j < 2; j++) {
                int ncol = n0 + wn * 32 + j * 16;
                int cc   = ncol + lr;
                #pragma unroll
                for (int r = 0; r < 4; r++) {
                    int row = orow + i * 16 + g * 4 + r;
                    float v = acc[i][j][r];
                    if (MODE == 0) {
                        if (ncol < 192)      out_q[(size_t)row * CC + cc]          = f2bf(v + bias[cc]);
                        else if (ncol < 384) out_ctx[(size_t)row * CC + (cc - 192)] = f2bf(v + bias[cc]);
                        else if (cc < NF)    out_g[(size_t)row * 4 + (cc - 384)]    = f2bf(v + bias[cc]);
                    } else if (MODE == 1) {
                        float val = v + bias[cc] + bf2f(gates_in[(size_t)row * 4 + 3]) * hg[bidx * CC + cc];
                        val *= bf2f(q_in[(size_t)row * CC + cc]);
                        out_q[(size_t)row * CC + cc] = f2bf(val);
                    } else {
                        out_f[(size_t)row * CC + cc] = v + bias[cc] + x_in[(size_t)row * CC + cc];
                    }
                }
            }
        }
    }
}

// ---------------- Depthwise conv v5: 8 x-pixels x 8 ch per thread, pk-f32 -----
// LVL 0 (F=3): out = gelu(conv3(in))                      [writes c3 plane]
// LVL 1 (F=5): out = gelu(conv5(c3)); ctx = g0*c3c + g1*out  [writes c5 + ctx01]
// LVL 2 (F=7): c7 = gelu(conv7(c5)); ctx += g2*c7; block partial sums of c7
template<int F, int LVL>
__global__ __launch_bounds__(256) void convv2_kernel(const us16* __restrict__ in,
                            us16* __restrict__ outp,
                            us16* __restrict__ ctx,
                            const us16* __restrict__ gates,
                            const us16* __restrict__ kwT,
                            float* __restrict__ partial) {
    constexpr int P  = F / 2;
    constexpr int NW = F + 7;          // row vectors per ky: XT + F - 1, XT = 8
    __shared__ __align__(16) us16 kws[F * F * CC];   // LVL2: reused as psum later
    int tid = threadIdx.x;
    int lb  = (blockIdx.x & 7) * 192 + (blockIdx.x >> 3);  // 1536 blocks; XCD owns 1 image
    for (int t = tid; t < F * F * CC / 8; t += 256)
        ((bf16x8*)kws)[t] = ((const bf16x8*)kwT)[t];
    __syncthreads();
    int idx  = lb * 256 + tid;                    // over (MM/8)*24
    int cg   = idx % 24;
    int rest = idx / 24;                          // b*2048 + y*16 + x8
    int x8 = rest & 15;
    int y0 = (rest >> 4) & 127;
    int b  = rest >> 11;
    int x0 = x8 * 8;
    f32x2 acc[8][4] = {};
    const us16* inb = in + (size_t)b * LLEN * CC + cg * 8;
    for (int ky = 0; ky < F; ky++) {
        int yy = y0 + ky - P;
        if (yy < 0 || yy > 127) continue;
        const us16* rp = inb + (size_t)yy * WID * CC;
        // per-ky weights in regs
        f32x2 w[F][4];
        #pragma unroll
        for (int kx = 0; kx < F; kx++) {
            uint4 wv = *(const uint4*)(kws + (ky * F + kx) * CC + cg * 8);
            w[kx][0] = unpk2(wv.x); w[kx][1] = unpk2(wv.y);
            w[kx][2] = unpk2(wv.z); w[kx][3] = unpk2(wv.w);
        }
        #pragma unroll
        for (int i = 0; i < NW; i++) {
            int xx = x0 - P + i;
            f32x2 rv[4];
            if (xx >= 0 && xx <= 127) {
                uint4 v = *(const uint4*)(rp + (size_t)xx * CC);
                rv[0] = unpk2(v.x); rv[1] = unpk2(v.y);
                rv[2] = unpk2(v.z); rv[3] = unpk2(v.w);
            } else {
                rv[0] = rv[1] = rv[2] = rv[3] = (f32x2){0.0f, 0.0f};
            }
            #pragma unroll
            for (int px = 0; px < 8; px++) {
                constexpr int dummy = 0; (void)dummy;
                int kx = i - px;
                if (kx >= 0 && kx < F) {
                    acc[px][0] += rv[0] * w[kx][0];
                    acc[px][1] += rv[1] * w[kx][1];
                    acc[px][2] += rv[2] * w[kx][2];
                    acc[px][3] += rv[3] * w[kx][3];
                }
            }
        }
    }
    int pix = (b * HGT + y0) * WID + x0;
    size_t obase = (size_t)pix * CC + cg * 8;
    if constexpr (LVL == 0) {
        #pragma unroll
        for (int px = 0; px < 8; px++) {
            uint4 ov;
            unsigned* po = &ov.x;
            #pragma unroll
            for (int q = 0; q < 4; q++)
                po[q] = (unsigned)f2bf(gelu_f(acc[px][q][0]))
                      | ((unsigned)f2bf(gelu_f(acc[px][q][1])) << 16);
            *(uint4*)(outp + obase + (size_t)px * CC) = ov;
        }
    } else if constexpr (LVL == 1) {
        #pragma unroll
        for (int px = 0; px < 8; px++) {
            unsigned gv = *(const unsigned*)(gates + (size_t)(pix + px) * 4);
            float g0 = bf2f((us16)(gv & 0xffffu));
            float g1 = bf2f((us16)(gv >> 16));
            // c3 center = input plane at this output pixel
            uint4 c3v = *(const uint4*)(inb + ((size_t)y0 * WID + x0 + px) * CC);
            const unsigned* pc = &c3v.x;
            uint4 ov, cv;
            unsigned* po = &ov.x;
            unsigned* pv = &cv.x;
            #pragma unroll
            for (int q = 0; q < 4; q++) {
                f32x2 c3 = unpk2(pc[q]);
                float v5a = gelu_f(acc[px][q][0]);
                float v5b = gelu_f(acc[px][q][1]);
                po[q] = (unsigned)f2bf(v5a) | ((unsigned)f2bf(v5b) << 16);
                pv[q] = (unsigned)f2bf(g0 * c3[0] + g1 * v5a)
                      | ((unsigned)f2bf(g0 * c3[1] + g1 * v5b) << 16);
            }
            *(uint4*)(outp + obase + (size_t)px * CC) = ov;
            *(uint4*)(ctx  + obase + (size_t)px * CC) = cv;
        }
    } else {
        f32x2 csum[4] = {};
        #pragma unroll
        for (int px = 0; px < 8; px++) {
            float g2 = bf2f(gates[(size_t)(pix + px) * 4 + 2]);
            uint4 cv = *(const uint4*)(ctx + obase + (size_t)px * CC);
            const unsigned* pc = &cv.x;
            uint4 ov;
            unsigned* po = &ov.x;
            #pragma unroll
            for (int q = 0; q < 4; q++) {
                f32x2 cprev = unpk2(pc[q]);
                float c7a = gelu_f(acc[px][q][0]);
                float c7b = gelu_f(acc[px][q][1]);
                csum[q][0] += c7a;
                csum[q][1] += c7b;
                po[q] = (unsigned)f2bf(cprev[0] + g2 * c7a)
                      | ((unsigned)f2bf(cprev[1] + g2 * c7b) << 16);
            }
            *(uint4*)(ctx + obase + (size_t)px * CC) = ov;
        }
        __syncthreads();                             // done with kws taps
        float (*psum)[8] = (float (*)[8])kws;        // overlay (8 KB <= 18.4 KB)
        #pragma unroll
        for (int q = 0; q < 4; q++) {
            psum[tid][q * 2]     = csum[q][0];
            psum[tid][q * 2 + 1] = csum[q][1];
        }
        __syncthreads();
        if (tid < 192) {
            int j = tid & 7, cgw = tid >> 3;
            int t0 = (cgw - (lb * 256) % 24) % 24;
            if (t0 < 0) t0 += 24;
            float s = 0.0f;
            for (int t = t0; t < 256; t += 24) s += psum[t][j];
            partial[(size_t)lb * CC + tid] = s;   // c == tid (cgw*8 + j)
        }
    }
}

// ---------------- Global mean finish + hg = h_w @ gelu(mean), 1 block/image ---
__global__ __launch_bounds__(192) void gmean2_kernel(const float* __restrict__ partial,
                                                     const float* __restrict__ h_w,
                                                     float* __restrict__ hg) {
    __shared__ float ctxg[CC];
    int b = blockIdx.x, c = threadIdx.x;
    const float* pb = partial + (size_t)b * 192 * CC + c;
    float s = 0.0f;
    for (int k = 0; k < 192; k++) s += pb[(size_t)k * CC];
    ctxg[c] = gelu_f(s * (1.0f / 16384.0f));
    __syncthreads();
    float a = 0.0f;
    for (int c2 = 0; c2 < CC; c2++) a += h_w[c * CC + c2] * ctxg[c2];
    hg[b * CC + c] = a;
}

// ---------------- fc1: hid = gelu(ln2 @ w1 + b1), 128x128 tile, 8 waves -------
__global__ __launch_bounds__(512, 4) void fc1_kernel(const us16* __restrict__ A,
        const us16* __restrict__ w1T, const float* __restrict__ bias,
        us16* __restrict__ hid0, us16* __restrict__ hid1) {
    __shared__ __align__(16) char Asm[128 * 384];
    int id  = blockIdx.x;
    int swz = (id & 7) * 384 + (id >> 3);   // XCD-chunked: m-contiguous per XCD
    int mt  = swz / 6, nt = swz % 6;
    int m0 = mt * 128;
    int n0 = nt * 128;
    int tid = threadIdx.x, lane = tid & 63, w = tid >> 6;
    int wm = w >> 2, wn = w & 3, g = lane >> 4, lr = lane & 15;

    const char* Agl = (const char*)(A + (size_t)m0 * CC);
    #pragma unroll
    for (int i = 0; i < 6; i++) {
        int wl   = w * 6 + i;                  // 0..47
        int byte = wl * 1024 + lane * 16;
        int row  = byte / 384;
        int off  = byte - row * 384;
        int soff = off ^ ((row & 7) << 4);
        gload_lds16(Agl + (size_t)row * 384 + soff, Asm + wl * 1024);
    }
    const us16* Bb = w1T + (size_t)(n0 + wn * 32 + lr) * CC;
    bf16x8 bfr[6][2];
    #pragma unroll
    for (int kk = 0; kk < 6; kk++)
        #pragma unroll
        for (int j = 0; j < 2; j++)
            bfr[kk][j] = *(const bf16x8*)(Bb + (size_t)j * 16 * CC + kk * 32 + g * 8);

    __syncthreads();

    f32x4 acc[4][2] = {};
    #pragma unroll
    for (int kk = 0; kk < 6; kk++) {
        int k2 = (kk * 32 + g * 8) * 2;
        bf16x8 a[4];
        #pragma unroll
        for (int i = 0; i < 4; i++) {
            int row = wm * 64 + i * 16 + lr;
            a[i] = *(const bf16x8*)(Asm + row * 384 + (k2 ^ ((row & 7) << 4)));
        }
        #pragma unroll
        for (int j = 0; j < 2; j++) {
            acc[0][j] = __builtin_amdgcn_mfma_f32_16x16x32_bf16(a[0], bfr[kk][j], acc[0][j], 0, 0, 0);
            acc[1][j] = __builtin_amdgcn_mfma_f32_16x16x32_bf16(a[1], bfr[kk][j], acc[1][j], 0, 0, 0);
            acc[2][j] = __builtin_amdgcn_mfma_f32_16x16x32_bf16(a[2], bfr[kk][j], acc[2][j], 0, 0, 0);
            acc[3][j] = __builtin_amdgcn_mfma_f32_16x16x32_bf16(a[3], bfr[kk][j], acc[3][j], 0, 0, 0);
        }
    }
    us16* hidp = (m0 & 32768) ? hid1 : hid0;
    int ml = (m0 & 32767) + wm * 64;
    #pragma unroll
    for (int i = 0; i < 4; i++) {
        #pragma unroll
        for (int j = 0; j < 2; j++) {
            int col = n0 + wn * 32 + j * 16 + lr;
            float fb = bias[col];
            #pragma unroll
            for (int r = 0; r < 4; r++) {
                int row = ml + i * 16 + g * 4 + r;
                hidp[(size_t)row * HIDN + col] = f2bf(gelu_f(acc[i][j][r] + fb));
            }
        }
    }
}

// ---------------- fc2: out += hid @ w2 + b2, 128x192 tile, K=768 in 4 chunks --
__global__ __launch_bounds__(512, 4) void fc2_kernel(const us16* __restrict__ hid0,
        const us16* __restrict__ hid1, const us16* __restrict__ w2T,
        const float* __restrict__ bias, float* __restrict__ io) {
    __shared__ __align__(16) char Asm[128 * 384];
    int m0 = blockIdx.x * 128;
    int tid = threadIdx.x, lane = tid & 63, w = tid >> 6;
    int wm = w >> 2, wn = w & 3, g = lane >> 4, lr = lane & 15;
    const us16* hidp = (m0 & 32768) ? hid1 : hid0;
    const char* Agl = (const char*)(hidp + (size_t)(m0 & 32767) * HIDN);

    f32x4 acc[4][3] = {};
    for (int c = 0; c < 4; c++) {
        #pragma unroll
        for (int i = 0; i < 6; i++) {
            int wl   = w * 6 + i;
            int byte = wl * 1024 + lane * 16;
            int row  = byte / 384;
            int off  = byte - row * 384;
            int soff = off ^ ((row & 7) << 4);
            gload_lds16(Agl + (size_t)row * 1536 + c * 384 + soff, Asm + wl * 1024);
        }
        __syncthreads();                       // DMA drained (vmcnt 0)
        #pragma unroll
        for (int kk = 0; kk < 6; kk++) {
            int k2 = (kk * 32 + g * 8) * 2;
            bf16x8 a[4];
            #pragma unroll
            for (int i = 0; i < 4; i++) {
                int row = wm * 64 + i * 16 + lr;
                a[i] = *(const bf16x8*)(Asm + row * 384 + (k2 ^ ((row & 7) << 4)));
            }
            #pragma unroll
            for (int j = 0; j < 3; j++) {
                bf16x8 bv = *(const bf16x8*)(w2T + (size_t)(wn * 48 + j * 16 + lr) * HIDN
                                             + c * 192 + kk * 32 + g * 8);
                acc[0][j] = __builtin_amdgcn_mfma_f32_16x16x32_bf16(a[0], bv, acc[0][j], 0, 0, 0);
                acc[1][j] = __builtin_amdgcn_mfma_f32_16x16x32_bf16(a[1], bv, acc[1][j], 0, 0, 0);
                acc[2][j] = __builtin_amdgcn_mfma_f32_16x16x32_bf16(a[2], bv, acc[2][j], 0, 0, 0);
                acc[3][j] = __builtin_amdgcn_mfma_f32_16x16x32_bf16(a[3], bv, acc[3][j], 0, 0, 0);
            }
        }
        __syncthreads();                       // safe to overwrite Asm
    }
    #pragma unroll
    for (int i = 0; i < 4; i++) {
        #pragma unroll
        for (int j = 0; j < 3; j++) {
            int col = wn * 48 + j * 16 + lr;
            float fb = bias[col];
            #pragma unroll
            for (int r = 0; r < 4; r++) {
                int row = m0 + wm * 64 + i * 16 + g * 4 + r;
                io[(size_t)row * CC + col] += acc[i][j][r] + fb;
            }
        }
    }
}

extern "C" void kernel_launch(void* const* d_in, const int* in_sizes, int n_in,
                              void* d_out, int out_size, void* d_ws, size_t ws_size,
                              hipStream_t stream) {
    const float* x      = (const float*)d_in[0];
    const float* ln1_g  = (const float*)d_in[1];
    const float* ln1_b  = (const float*)d_in[2];
    const float* f_w    = (const float*)d_in[3];
    const float* f_b    = (const float*)d_in[4];
    const float* fk0    = (const float*)d_in[5];
    const float* fk1    = (const float*)d_in[6];
    const float* fk2    = (const float*)d_in[7];
    const float* h_w    = (const float*)d_in[8];
    const float* h_b    = (const float*)d_in[9];
    const float* proj_w = (const float*)d_in[10];
    const float* proj_b = (const float*)d_in[11];
    const float* ln2_g  = (const float*)d_in[12];
    const float* ln2_b  = (const float*)d_in[13];
    const float* fc1_w  = (const float*)d_in[14];
    const float* fc1_b  = (const float*)d_in[15];
    const float* fc2_w  = (const float*)d_in[16];
    const float* fc2_b  = (const float*)d_in[17];
    float* outp = (float*)d_out;

    char* ws = (char*)d_ws;
    const size_t S = (size_t)MM * CC * 2;          // 50,331,648 B (one bf16 plane)
    us16* t_buf   = (us16*)(ws);                   // t / xq ; later hid plane 0
    us16* q_buf   = (us16*)(ws + S);               // q ; later ln2 output
    us16* ctx_all = (us16*)(ws + 2 * S);           // ctx01/ctx_all ; later hid plane 1
    us16* gates   = (us16*)(ws + 3 * S);
    float* hg      = (float*)(ws + 3 * S + 1048576);
    us16* fwT   = (us16*)(ws + 3 * S + 1048576 + 786432 + 6144);
    us16* hwB   = fwT + 86016;
    us16* projT = hwB + 36864;
    us16* w1T   = projT + 36864;
    us16* w2T   = w1T + 147456;
    us16* kw0T  = w2T + 147456;
    us16* kw1T  = kw0T + 1728;
    us16* kw2T  = kw1T + 4800;
    // conv planes live in d_out (dead until mgemm<2> rewrites it fully)
    us16* ctxA = (us16*)d_out;                          // conv input, then c5
    us16* ctxB = (us16*)d_out + (size_t)MM * CC;        // c3
    float* partial = (float*)ctxB;                      // reused after c3 is dead

    wcvt_kernel<<<1839, 256, 0, stream>>>(f_w, h_w, proj_w, fc1_w, fc2_w,
                                          fk0, fk1, fk2,
                                          fwT, hwB, projT, w1T, w2T, kw0T, kw1T, kw2T);

    ln_kernel<<<MM / 4, 256, 0, stream>>>(x, ln1_g, ln1_b, t_buf);

    mgemm_kernel<0><<<1024, 256, 0, stream>>>(
        t_buf, fwT, f_b, q_buf, ctxA, gates, nullptr, nullptr, nullptr, nullptr, nullptr);

    convv2_kernel<3, 0><<<1536, 256, 0, stream>>>(ctxA, ctxB, nullptr, nullptr, kw0T, nullptr);
    convv2_kernel<5, 1><<<1536, 256, 0, stream>>>(ctxB, ctxA, ctx_all, gates, kw1T, nullptr);
    convv2_kernel<7, 2><<<1536, 256, 0, stream>>>(ctxA, nullptr, ctx_all, gates, kw2T, partial);

    gmean2_kernel<<<8, 192, 0, stream>>>(partial, h_w, hg);

    mgemm_kernel<1><<<1024, 256, 0, stream>>>(
        ctx_all, hwB, h_b, t_buf, nullptr, nullptr, q_buf, gates, hg, nullptr, nullptr);

    mgemm_kernel<2><<<1024, 256, 0, stream>>>(
        t_buf, projT, proj_b, nullptr, nullptr, nullptr, nullptr, nullptr, nullptr, x, outp);

    // ---- MLP as two staged GEMMs over two M-halves ----
    ln_kernel<<<MM / 4, 256, 0, stream>>>(outp, ln2_g, ln2_b, q_buf);

    for (int h = 0; h < 2; h++) {
        const us16* Ah = q_buf + (size_t)h * 65536 * CC;
        float* ioh     = outp  + (size_t)h * 65536 * CC;
        fc1_kernel<<<3072, 512, 0, stream>>>(Ah, w1T, fc1_b, t_buf, ctx_all);
        fc2_kernel<<<512, 512, 0, stream>>>(t_buf, ctx_all, w2T, fc2_b, ioh);
    }
}